// Round 16
// baseline (519.554 us; speedup 1.0000x reference)
//
#include <hip/hip_runtime.h>
#include <stdint.h>

#define B_DIM 4
#define T_DIM 2048
#define C_DIM 2048
#define NH 16
#define HD 128

typedef unsigned short u16;
typedef __attribute__((ext_vector_type(8))) short short8;
typedef __attribute__((ext_vector_type(8))) u16 ushort8;
typedef __attribute__((ext_vector_type(4))) u16 u16x4;
typedef __attribute__((ext_vector_type(2))) uint32_t u32x2;
typedef __attribute__((ext_vector_type(4))) float f32x4;

// scale / sqrt(128) * log2(e), folded into Q-projection epilogue
#define QSCALE (0.08838834764831845f * 1.4426950408889634f)

__device__ __forceinline__ u16 f2bf(float f) {
  uint32_t u = __builtin_bit_cast(uint32_t, f);
  u = (u + 0x7FFFu + ((u >> 16) & 1u)) >> 16;
  return (u16)u;
}

__device__ __forceinline__ uint32_t cvtpk(float lo, float hi) {
  uint32_t r;
  asm("v_cvt_pk_bf16_f32 %0, %1, %2" : "=v"(r) : "v"(lo), "v"(hi));
  return r;
}

__device__ __forceinline__ void gload16(const void* g, void* l) {
  __builtin_amdgcn_global_load_lds(
      (const __attribute__((address_space(1))) void*)g,
      (__attribute__((address_space(3))) void*)l, 16, 0, 0);
}

__device__ __forceinline__ void wait_vm2() { asm volatile("s_waitcnt vmcnt(2)" ::: "memory"); }
__device__ __forceinline__ void wait_vm4() { asm volatile("s_waitcnt vmcnt(4)" ::: "memory"); }
__device__ __forceinline__ void wait_vm0() { asm volatile("s_waitcnt vmcnt(0)" ::: "memory"); }
__device__ __forceinline__ void wait_lg0() {
  asm volatile("s_waitcnt lgkmcnt(0)" ::: "memory");
  __builtin_amdgcn_sched_barrier(0);
}

// ---------------- fused cast f32 -> bf16 (x + 4 weights) ----------------
__global__ void cast_all_kernel(const float* __restrict__ x,
                                const float* __restrict__ s0, const float* __restrict__ s1,
                                const float* __restrict__ s2, const float* __restrict__ s3,
                                u16* __restrict__ xd,
                                u16* __restrict__ d0, u16* __restrict__ d1,
                                u16* __restrict__ d2, u16* __restrict__ d3) {
  const int bid = blockIdx.x;
  const float* s; u16* d; int blk;
  if (bid < 8192) { s = x; d = xd; blk = bid; }
  else {
    const int a = (bid - 8192) >> 11;
    s = a == 0 ? s0 : a == 1 ? s1 : a == 2 ? s2 : s3;
    d = a == 0 ? d0 : a == 1 ? d1 : a == 2 ? d2 : d3;
    blk = (bid - 8192) & 2047;
  }
  int i = (blk * 256 + threadIdx.x) * 8;
  f32x4 va = *(const f32x4*)(s + i);
  f32x4 vb = *(const f32x4*)(s + i + 4);
  ushort8 o;
  o[0] = f2bf(va[0]); o[1] = f2bf(va[1]); o[2] = f2bf(va[2]); o[3] = f2bf(va[3]);
  o[4] = f2bf(vb[0]); o[5] = f2bf(vb[1]); o[6] = f2bf(vb[2]); o[7] = f2bf(vb[3]);
  *(ushort8*)(d + i) = o;
}

// ============ shared 256x256 GEMM core (BK=64, 8 waves, 4 phases) ==========
#define GEMM_CORE(Aptr, Bptr, KDIM)                                            \
  const int tid = threadIdx.x, wid = tid >> 6, lane = tid & 63;                \
  const int wm = wid >> 2, wn = wid & 3;                                       \
  const int srow = (wid << 3) + (lane >> 3);                                   \
  const int scol = ((lane & 7) ^ (lane >> 3)) << 3;                            \
  const u16* Ag = Aptr + (size_t)(bm + srow) * KDIM + scol;                    \
  const u16* Bg = Bptr + (size_t)(bn + srow) * KDIM + scol;                    \
  const int sbase = wid << 9;                                                  \
  const int l15 = lane & 15;                                                   \
  const int o0 = ((lane >> 4) ^ (lane & 7)) << 3;                              \
  const int o1 = ((4 | (lane >> 4)) ^ (lane & 7)) << 3;                        \
  const int ar = ((wm << 7) + l15) << 6;                                       \
  const int br = ((wn << 6) + l15) << 6;                                       \
  f32x4 acc[8][4];                                                             \
  f32x4 zero4 = {0.f, 0.f, 0.f, 0.f};                                          \
  _Pragma("unroll") for (int i = 0; i < 8; ++i)                                \
    _Pragma("unroll") for (int n = 0; n < 4; ++n) acc[i][n] = zero4;           \
  auto stA = [&](int slot, int tc, int r0, int r1) {                           \
    gload16(Ag + (size_t)r0 * KDIM + tc, &lds[slot][(r0 << 6) + sbase]);       \
    gload16(Ag + (size_t)r1 * KDIM + tc, &lds[slot][(r1 << 6) + sbase]);       \
  };                                                                           \
  auto stB = [&](int slot, int tc, int r0, int r1) {                           \
    gload16(Bg + (size_t)r0 * KDIM + tc, &lds[slot][(r0 << 6) + sbase]);       \
    gload16(Bg + (size_t)r1 * KDIM + tc, &lds[slot][(r1 << 6) + sbase]);       \
  };                                                                           \
  stB(2, 0, 0, 64); stB(2, 0, 128, 192);                                       \
  stA(0, 0, 0, 128); stA(0, 0, 64, 192);                                       \
  short8 af[4], bf[4];                                                         \
  const int NT = KDIM >> 6;                                                    \
  _Pragma("unroll 2") for (int t = 0; t < NT; ++t) {                           \
    const int p = t & 1, q = p ^ 1;                                            \
    const int tc = ((t + 1) & (NT - 1)) << 6;                                  \
    wait_vm2();                                                                \
    __builtin_amdgcn_s_barrier();                                              \
    _Pragma("unroll") for (int i = 0; i < 4; ++i)                              \
      af[i] = *(const short8*)&lds[p][ar + (i << 10) + o0];                    \
    _Pragma("unroll") for (int n = 0; n < 4; ++n)                              \
      bf[n] = *(const short8*)&lds[2 + p][br + (n << 10) + o0];                \
    stB(2 + q, tc, 0, 64); stB(2 + q, tc, 128, 192);                           \
    __builtin_amdgcn_s_barrier();                                              \
    wait_lg0();                                                                \
    __builtin_amdgcn_s_setprio(1);                                             \
    _Pragma("unroll") for (int i = 0; i < 4; ++i)                              \
      _Pragma("unroll") for (int n = 0; n < 4; ++n)                            \
        acc[i][n] = __builtin_amdgcn_mfma_f32_16x16x32_bf16(af[i], bf[n], acc[i][n], 0, 0, 0); \
    __builtin_amdgcn_s_setprio(0);                                             \
    wait_vm4();                                                                \
    __builtin_amdgcn_s_barrier();                                              \
    _Pragma("unroll") for (int i = 0; i < 4; ++i)                              \
      af[i] = *(const short8*)&lds[p][ar + 4096 + (i << 10) + o0];             \
    stA(q, tc, 0, 128); stA(q, tc, 64, 192);                                   \
    __builtin_amdgcn_s_barrier();                                              \
    wait_lg0();                                                                \
    __builtin_amdgcn_s_setprio(1);                                             \
    _Pragma("unroll") for (int i = 0; i < 4; ++i)                              \
      _Pragma("unroll") for (int n = 0; n < 4; ++n)                            \
        acc[4 + i][n] = __builtin_amdgcn_mfma_f32_16x16x32_bf16(af[i], bf[n], acc[4 + i][n], 0, 0, 0); \
    __builtin_amdgcn_s_setprio(0);                                             \
    __builtin_amdgcn_s_barrier();                                              \
    _Pragma("unroll") for (int i = 0; i < 4; ++i)                              \
      af[i] = *(const short8*)&lds[p][ar + (i << 10) + o1];                    \
    _Pragma("unroll") for (int n = 0; n < 4; ++n)                              \
      bf[n] = *(const short8*)&lds[2 + p][br + (n << 10) + o1];                \
    __builtin_amdgcn_s_barrier();                                              \
    wait_lg0();                                                                \
    __builtin_amdgcn_s_setprio(1);                                             \
    _Pragma("unroll") for (int i = 0; i < 4; ++i)                              \
      _Pragma("unroll") for (int n = 0; n < 4; ++n)                            \
        acc[i][n] = __builtin_amdgcn_mfma_f32_16x16x32_bf16(af[i], bf[n], acc[i][n], 0, 0, 0); \
    __builtin_amdgcn_s_setprio(0);                                             \
    __builtin_amdgcn_s_barrier();                                              \
    _Pragma("unroll") for (int i = 0; i < 4; ++i)                              \
      af[i] = *(const short8*)&lds[p][ar + 4096 + (i << 10) + o1];             \
    __builtin_amdgcn_s_barrier();                                              \
    wait_lg0();                                                                \
    __builtin_amdgcn_s_setprio(1);                                             \
    _Pragma("unroll") for (int i = 0; i < 4; ++i)                              \
      _Pragma("unroll") for (int n = 0; n < 4; ++n)                            \
        acc[4 + i][n] = __builtin_amdgcn_mfma_f32_16x16x32_bf16(af[i], bf[n], acc[4 + i][n], 0, 0, 0); \
    __builtin_amdgcn_s_setprio(0);                                             \
  }                                                                            \
  wait_vm0();

// MODE 0: bf16 out. MODE 1: f32 out. MODE 2: bf16 V^T out. MODE 3: bf16*QSCALE.
template<int MODE>
__global__ __launch_bounds__(512, 2)
void gemm256(const u16* __restrict__ A, const u16* __restrict__ Bw,
             void* __restrict__ Cout) {
  __shared__ __align__(16) u16 lds[4][16384];
  const int swz = (blockIdx.x & 7) * 32 + (blockIdx.x >> 3);
  const int bm = (swz >> 3) << 8;
  const int bn = (swz & 7) << 8;

  GEMM_CORE(A, Bw, 2048)

  const int orow = (lane >> 4) << 2;
  const int ocol = lane & 15;
#pragma unroll
  for (int mi = 0; mi < 8; ++mi)
#pragma unroll
    for (int ni = 0; ni < 4; ++ni) {
      f32x4 v = acc[mi][ni];
      const int row0 = (wm << 7) + mi * 16 + orow;
      const int col = bn + (wn << 6) + ni * 16 + ocol;
      if (MODE == 2) {
        u16* C = (u16*)Cout;
        size_t base = (size_t)(bm >> 11) * ((size_t)T_DIM * C_DIM) +
                      (size_t)col * T_DIM + (size_t)((bm & 2047) + row0);
        u16x4 o;
        o[0] = f2bf(v[0]); o[1] = f2bf(v[1]); o[2] = f2bf(v[2]); o[3] = f2bf(v[3]);
        *(u16x4*)&C[base] = o;
      } else {
        size_t base = (size_t)(bm + row0) * C_DIM + col;
        if (MODE == 1) {
          float* C = (float*)Cout;
#pragma unroll
          for (int r = 0; r < 4; ++r) C[base + (size_t)r * C_DIM] = v[r];
        } else {
          u16* C = (u16*)Cout;
          const float sc = (MODE == 3) ? QSCALE : 1.0f;
#pragma unroll
          for (int r = 0; r < 4; ++r) C[base + (size_t)r * C_DIM] = f2bf(v[r] * sc);
        }
      }
    }
}

// ------ causal flash attention: KVBLK=32, 4 waves x 32 q-rows, 4 blk/CU ----
// grid 1024 = 64 bh x 16 q-blocks (no pairing). LDS 37KB -> 4 blocks/CU.
// qtab equalizes per-CU work assuming round-robin block->CU (sums = 136/CU),
// longest q-blocks dispatched first. bh low octal = f&7 keeps one head's
// blocks on one XCD. K [32][128] + V [128][32] linear, gload_lds staged,
// both-sides XOR swizzle (K: unit^=row&7; V: unit^=row&3). Race-free
// schedule {vm0; barrier; stage(t+1); compute(cur)}.
__global__ __launch_bounds__(256, 4)
void attn_kernel(const u16* __restrict__ Qg, const u16* __restrict__ Kg,
                 const u16* __restrict__ VtG, u16* __restrict__ Y) {
  __shared__ __align__(16) u16 Klds[2][32 * 128];
  __shared__ __align__(16) u16 Vlds[2][128 * 32];
  __shared__ __align__(16) u16 Plds[4][16][40];
  const int f = blockIdx.x;
  const int bh = ((f & 7) << 3) | ((f >> 3) & 7);
  const int qi = f >> 6;
  const int qtab[16] = {0, 1, 2, 3, 7, 6, 5, 4, 8, 9, 10, 11, 15, 14, 13, 12};
  const int qb = (15 - qtab[qi]) << 7;
  const int b = bh >> 4, h = bh & 15;
  const size_t qkbase = (size_t)b * T_DIM * C_DIM + (size_t)h * HD;
  const size_t vtbase = (size_t)b * T_DIM * C_DIM + (size_t)h * HD * T_DIM;
  const int tid = threadIdx.x, wid = tid >> 6, lane = tid & 63;
  const int l15 = lane & 15, g = lane >> 4;

  // K staging: wave w rows w*8..+7; gload j: row += j*4 + (lane>>4);
  // source unit pre-swizzled (lane&15) ^ (j*4 + (lane>>4)); dest linear.
  const int krow = (wid << 3) + (lane >> 4);
  const u16* Kge = Kg + qkbase + (size_t)krow * C_DIM + (((lane & 15) ^ (lane >> 4)) << 3);
  const u16* Kgo = Kg + qkbase + (size_t)krow * C_DIM + (((lane & 15) ^ 4 ^ (lane >> 4)) << 3);
  // V staging: wave w rows w*32..+31; gload j: row += j*16 + (lane>>2);
  // source unit (lane&3) ^ ((lane>>2)&3).
  const int vrow = (wid << 5) + (lane >> 2);
  const u16* Vgp = VtG + vtbase + (size_t)vrow * T_DIM + (((lane & 3) ^ ((lane >> 2) & 3)) << 3);

  auto stageK = [&](int buf, int kb) {
    u16* L = &Klds[buf][wid << 10];
    gload16(Kge + (size_t)kb * C_DIM, L);
    gload16(Kgo + (size_t)(kb + 4) * C_DIM, L + 512);
  };
  auto stageV = [&](int buf, int kb) {
    u16* L = &Vlds[buf][wid << 10];
    gload16(Vgp + kb, L);
    gload16(Vgp + (size_t)16 * T_DIM + kb, L + 512);
  };

  const int rlo = qb + wid * 32;
  stageK(0, 0); stageV(0, 0);
  short8 qf[2][4];
#pragma unroll
  for (int rg = 0; rg < 2; ++rg) {
    const u16* qp = Qg + qkbase + (size_t)(rlo + rg * 16 + l15) * C_DIM + g * 8;
#pragma unroll
    for (int dc = 0; dc < 4; ++dc) qf[rg][dc] = *(const short8*)(qp + dc * 32);
  }
  f32x4 zero4 = {0.f, 0.f, 0.f, 0.f};
  f32x4 ao[2][8];
#pragma unroll
  for (int rg = 0; rg < 2; ++rg)
#pragma unroll
    for (int i = 0; i < 8; ++i) ao[rg][i] = zero4;
  float m_run[2] = {-1e30f, -1e30f};
  float l_lane[2] = {0.f, 0.f};
  const int nt = (qb >> 5) + 4;

  int cur = 0;
  for (int t = 0; t < nt; ++t) {
    const int kb = t * 32;
    wait_vm0();                     // own buf[cur] stages (and t=0 qf) landed
    __builtin_amdgcn_s_barrier();   // all waves landed; buf[cur^1] reads done
    if (t + 1 < nt) { stageK(cur ^ 1, kb + 32); stageV(cur ^ 1, kb + 32); }

    if (kb <= rlo + 31) {
      const u16* Kb_ = &Klds[cur][0];
      const u16* Vb_ = &Vlds[cur][0];
      // S^T for both row-groups; kf shared. lane: q = rlo+rg*16+l15,
      // k = kb + jt*16 + g*4 + r
      f32x4 st[2][2];
      __builtin_amdgcn_s_setprio(1);
#pragma unroll
      for (int jt = 0; jt < 2; ++jt) {
        short8 kf[4];
#pragma unroll
        for (int dc = 0; dc < 4; ++dc)
          kf[dc] = *(const short8*)&Kb_[(jt * 16 + l15) * 128 + ((((dc << 2) | g) ^ (l15 & 7)) << 3)];
        f32x4 a0 = zero4, a1 = zero4;
#pragma unroll
        for (int dc = 0; dc < 4; ++dc) {
          a0 = __builtin_amdgcn_mfma_f32_16x16x32_bf16(kf[dc], qf[0][dc], a0, 0, 0, 0);
          a1 = __builtin_amdgcn_mfma_f32_16x16x32_bf16(kf[dc], qf[1][dc], a1, 0, 0, 0);
        }
        st[0][jt] = a0; st[1][jt] = a1;
      }
      __builtin_amdgcn_s_setprio(0);

      short8 pf[2];
#pragma unroll
      for (int rg = 0; rg < 2; ++rg) {
        const int rbase = rlo + rg * 16;
        if (kb + 31 > rbase) {
          const int qa = rbase + l15;
#pragma unroll
          for (int jt = 0; jt < 2; ++jt) {
            const int k0 = kb + jt * 16 + g * 4;
#pragma unroll
            for (int r = 0; r < 4; ++r)
              if (k0 + r > qa) st[rg][jt][r] = -3e38f;   // exp2 -> exactly 0
          }
        }

        float mxl = fmaxf(fmaxf(fmaxf(st[rg][0][0], st[rg][0][1]),
                                fmaxf(st[rg][0][2], st[rg][0][3])),
                          fmaxf(fmaxf(st[rg][1][0], st[rg][1][1]),
                                fmaxf(st[rg][1][2], st[rg][1][3])));
        if (__any(mxl > m_run[rg] + 8.0f)) {
          float mx = fmaxf(mxl, __shfl_xor(mxl, 16, 64));
          mx = fmaxf(mx, __shfl_xor(mx, 32, 64));
          float mn = fmaxf(m_run[rg], mx);
          float corr = __builtin_amdgcn_exp2f(m_run[rg] - mn);
          m_run[rg] = mn;
#pragma unroll
          for (int dc = 0; dc < 8; ++dc)
#pragma unroll
            for (int r = 0; r < 4; ++r) ao[rg][dc][r] *= corr;
          l_lane[rg] *= corr;
        }

        // P = exp2(S - m); pack to per-wave Plds (row pad 40 u16)
#pragma unroll
        for (int jt = 0; jt < 2; ++jt) {
          float p0 = __builtin_amdgcn_exp2f(st[rg][jt][0] - m_run[rg]);
          float p1 = __builtin_amdgcn_exp2f(st[rg][jt][1] - m_run[rg]);
          float p2 = __builtin_amdgcn_exp2f(st[rg][jt][2] - m_run[rg]);
          float p3 = __builtin_amdgcn_exp2f(st[rg][jt][3] - m_run[rg]);
          l_lane[rg] += (p0 + p1) + (p2 + p3);
          u32x2 w;
          w[0] = cvtpk(p0, p1);
          w[1] = cvtpk(p2, p3);
          *(u32x2*)&Plds[wid][l15][jt * 16 + g * 4] = w;
        }
        pf[rg] = *(const short8*)&Plds[wid][l15][g * 8];

        // O^T += V^T P^T for this rg (single k-block of 32)
        __builtin_amdgcn_s_setprio(1);
#pragma unroll
        for (int dc = 0; dc < 8; ++dc) {
          short8 vf = *(const short8*)&Vb_[(dc * 16 + l15) * 32 + (((g ^ (l15 & 3))) << 3)];
          ao[rg][dc] = __builtin_amdgcn_mfma_f32_16x16x32_bf16(vf, pf[rg], ao[rg][dc], 0, 0, 0);
        }
        __builtin_amdgcn_s_setprio(0);
      }
    }
    cur ^= 1;
  }

  // final l reduce + normalize + write Y
#pragma unroll
  for (int rg = 0; rg < 2; ++rg) {
    float l = l_lane[rg];
    l += __shfl_xor(l, 16, 64);
    l += __shfl_xor(l, 32, 64);
    const float rcp = 1.0f / l;
    u16* yp = Y + qkbase + (size_t)(rlo + rg * 16 + l15) * C_DIM + g * 4;
#pragma unroll
    for (int dc = 0; dc < 8; ++dc) {
      u32x2 w;
      w[0] = cvtpk(ao[rg][dc][0] * rcp, ao[rg][dc][1] * rcp);
      w[1] = cvtpk(ao[rg][dc][2] * rcp, ao[rg][dc][3] * rcp);
      *(u32x2*)&yp[dc * 16] = w;
    }
  }
}

extern "C" void kernel_launch(void* const* d_in, const int* in_sizes, int n_in,
                              void* d_out, int out_size, void* d_ws, size_t ws_size,
                              hipStream_t stream) {
  const float* x  = (const float*)d_in[0];
  const float* Wq = (const float*)d_in[1];
  const float* Wk = (const float*)d_in[2];
  const float* Wv = (const float*)d_in[3];
  const float* Wo = (const float*)d_in[4];
  float* out = (float*)d_out;

  const size_t SZX = (size_t)8192 * 2048;
  const size_t SZW = (size_t)2048 * 2048;
  u16* xb  = (u16*)d_ws;
  u16* Wqb = xb + SZX;
  u16* Wkb = Wqb + SZW;
  u16* Wvb = Wkb + SZW;
  u16* Wob = Wvb + SZW;
  u16* Qb  = Wob + SZW;   // Q (pre-scaled), overwritten in place by attn Y
  u16* Kb  = Qb + SZX;
  u16* Vb  = Kb + SZX;    // V^T in [b][n][t] layout

  cast_all_kernel<<<16384, 256, 0, stream>>>(x, Wq, Wk, Wv, Wo, xb, Wqb, Wkb, Wvb, Wob);

  gemm256<3><<<256, 512, 0, stream>>>(xb, Wqb, Qb);  // Q * scale*log2e
  gemm256<0><<<256, 512, 0, stream>>>(xb, Wkb, Kb);
  gemm256<2><<<256, 512, 0, stream>>>(xb, Wvb, Vb);  // V^T out

  attn_kernel<<<1024, 256, 0, stream>>>(Qb, Kb, Vb, Qb);

  gemm256<1><<<256, 512, 0, stream>>>(Qb, Wob, out);
}

// Round 17
// 429.342 us; speedup vs baseline: 1.2101x; 1.2101x over previous
//
#include <hip/hip_runtime.h>
#include <stdint.h>

#define B_DIM 4
#define T_DIM 2048
#define C_DIM 2048
#define NH 16
#define HD 128

typedef unsigned short u16;
typedef __attribute__((ext_vector_type(8))) short short8;
typedef __attribute__((ext_vector_type(8))) u16 ushort8;
typedef __attribute__((ext_vector_type(4))) u16 u16x4;
typedef __attribute__((ext_vector_type(2))) uint32_t u32x2;
typedef __attribute__((ext_vector_type(4))) float f32x4;

// scale / sqrt(128) * log2(e), folded into Q-projection epilogue
#define QSCALE (0.08838834764831845f * 1.4426950408889634f)

__device__ __forceinline__ u16 f2bf(float f) {
  uint32_t u = __builtin_bit_cast(uint32_t, f);
  u = (u + 0x7FFFu + ((u >> 16) & 1u)) >> 16;
  return (u16)u;
}

__device__ __forceinline__ uint32_t cvtpk(float lo, float hi) {
  uint32_t r;
  asm("v_cvt_pk_bf16_f32 %0, %1, %2" : "=v"(r) : "v"(lo), "v"(hi));
  return r;
}

__device__ __forceinline__ void gload16(const void* g, void* l) {
  __builtin_amdgcn_global_load_lds(
      (const __attribute__((address_space(1))) void*)g,
      (__attribute__((address_space(3))) void*)l, 16, 0, 0);
}

__device__ __forceinline__ void wait_vm2() { asm volatile("s_waitcnt vmcnt(2)" ::: "memory"); }
__device__ __forceinline__ void wait_vm0() { asm volatile("s_waitcnt vmcnt(0)" ::: "memory"); }
__device__ __forceinline__ void wait_lg0() {
  asm volatile("s_waitcnt lgkmcnt(0)" ::: "memory");
  __builtin_amdgcn_sched_barrier(0);
}

// ---------------- fused cast f32 -> bf16 (x + 4 weights) ----------------
__global__ void cast_all_kernel(const float* __restrict__ x,
                                const float* __restrict__ s0, const float* __restrict__ s1,
                                const float* __restrict__ s2, const float* __restrict__ s3,
                                u16* __restrict__ xd,
                                u16* __restrict__ d0, u16* __restrict__ d1,
                                u16* __restrict__ d2, u16* __restrict__ d3) {
  const int bid = blockIdx.x;
  const float* s; u16* d; int blk;
  if (bid < 8192) { s = x; d = xd; blk = bid; }
  else {
    const int a = (bid - 8192) >> 11;
    s = a == 0 ? s0 : a == 1 ? s1 : a == 2 ? s2 : s3;
    d = a == 0 ? d0 : a == 1 ? d1 : a == 2 ? d2 : d3;
    blk = (bid - 8192) & 2047;
  }
  int i = (blk * 256 + threadIdx.x) * 8;
  f32x4 va = *(const f32x4*)(s + i);
  f32x4 vb = *(const f32x4*)(s + i + 4);
  ushort8 o;
  o[0] = f2bf(va[0]); o[1] = f2bf(va[1]); o[2] = f2bf(va[2]); o[3] = f2bf(va[3]);
  o[4] = f2bf(vb[0]); o[5] = f2bf(vb[1]); o[6] = f2bf(vb[2]); o[7] = f2bf(vb[3]);
  *(ushort8*)(d + i) = o;
}

// ============ 256x256 GEMM, BK=32, 5-slot ring (A x3, B x2), 80KB =========
// 2 blocks/CU (the key change: r15's 128KB ran 1 block/CU, all sync exposed).
// Slots [256][32]u16; read unit = g ^ ((l15>>1)&3), source col pre-swizzled
// (tid&3)^((tid>>3)&3) -> 2-way bank access (free), both-sides rule.
// Per tile: {vmcnt(2) [keeps A(t+1) in flight]; barrier; read af0-3+bf0-3;
// stage B(t+1),A(t+2); lgkm0; 16 MFMA; read af4-7; lgkm0; 16 MFMA}.
// Issue order B-then-A makes the vmcnt(2) count exact. Wrap stages safe
// (target slot's last reader finished before preceding barrier).
// MODE 0: bf16 out. MODE 1: f32 out. MODE 2: bf16 V^T out. MODE 3: bf16*QSCALE.
template<int MODE>
__global__ __launch_bounds__(512, 2)
void gemm256(const u16* __restrict__ A, const u16* __restrict__ Bw,
             void* __restrict__ Cout) {
  __shared__ __align__(16) u16 Alds[3][8192];
  __shared__ __align__(16) u16 Blds[2][8192];
  const int swz = (blockIdx.x & 7) * 32 + (blockIdx.x >> 3);
  const int bm = (swz >> 3) << 8;
  const int bn = (swz & 7) << 8;
  const int tid = threadIdx.x, wid = tid >> 6, lane = tid & 63;
  const int wm = wid >> 2, wn = wid & 3;
  const int l15 = lane & 15, g = lane >> 4;

  const int srow = tid >> 2;                       // 0..127 (+128 for 2nd gload)
  const int scol = ((tid & 3) ^ ((tid >> 3) & 3)) << 3;
  const u16* Ag = A + (size_t)(bm + srow) * 2048 + scol;
  const u16* Bg = Bw + (size_t)(bn + srow) * 2048 + scol;
  const int sb = wid << 9;

  const int o = (g ^ ((l15 >> 1) & 3)) << 3;
  const int abase = ((wm << 7) + l15) << 5;
  const int bbase = ((wn << 6) + l15) << 5;

  f32x4 acc[8][4];
  f32x4 zero4 = {0.f, 0.f, 0.f, 0.f};
#pragma unroll
  for (int i = 0; i < 8; ++i)
#pragma unroll
    for (int n = 0; n < 4; ++n) acc[i][n] = zero4;

  auto stA = [&](int slot, int tc) {
    gload16(Ag + tc, &Alds[slot][sb]);
    gload16(Ag + (size_t)128 * 2048 + tc, &Alds[slot][sb + 4096]);
  };
  auto stB = [&](int slot, int tc) {
    gload16(Bg + tc, &Blds[slot][sb]);
    gload16(Bg + (size_t)128 * 2048 + tc, &Blds[slot][sb + 4096]);
  };

  // prologue (order matters for vmcnt): B0, A0, A1
  stB(0, 0); stA(0, 0); stA(1, 32);

  int sA = 0;                                      // t % 3
  for (int t = 0; t < 64; ++t) {
    wait_vm2();                                    // drains A(t),B(t); A(t+1) flies
    __builtin_amdgcn_s_barrier();
    short8 af[4], bf[4];
#pragma unroll
    for (int i = 0; i < 4; ++i) af[i] = *(const short8*)&Alds[sA][abase + (i << 9) + o];
#pragma unroll
    for (int n = 0; n < 4; ++n) bf[n] = *(const short8*)&Blds[t & 1][bbase + (n << 9) + o];
    stB((t + 1) & 1, ((t + 1) & 63) << 5);         // B one tile ahead
    {
      int s2 = sA + 2; if (s2 >= 3) s2 -= 3;       // (t+2) % 3
      stA(s2, ((t + 2) & 63) << 5);                // A two tiles ahead
    }
    wait_lg0();
    __builtin_amdgcn_s_setprio(1);
#pragma unroll
    for (int i = 0; i < 4; ++i)
#pragma unroll
      for (int n = 0; n < 4; ++n)
        acc[i][n] = __builtin_amdgcn_mfma_f32_16x16x32_bf16(af[i], bf[n], acc[i][n], 0, 0, 0);
    __builtin_amdgcn_s_setprio(0);
#pragma unroll
    for (int i = 0; i < 4; ++i) af[i] = *(const short8*)&Alds[sA][abase + 2048 + (i << 9) + o];
    wait_lg0();
    __builtin_amdgcn_s_setprio(1);
#pragma unroll
    for (int i = 0; i < 4; ++i)
#pragma unroll
      for (int n = 0; n < 4; ++n)
        acc[4 + i][n] = __builtin_amdgcn_mfma_f32_16x16x32_bf16(af[i], bf[n], acc[4 + i][n], 0, 0, 0);
    __builtin_amdgcn_s_setprio(0);
    ++sA; if (sA == 3) sA = 0;
  }
  wait_vm0();

  const int orow = g << 2;
  const int ocol = l15;
#pragma unroll
  for (int mi = 0; mi < 8; ++mi)
#pragma unroll
    for (int ni = 0; ni < 4; ++ni) {
      f32x4 v = acc[mi][ni];
      const int row0 = (wm << 7) + mi * 16 + orow;
      const int col = bn + (wn << 6) + ni * 16 + ocol;
      if (MODE == 2) {
        u16* C = (u16*)Cout;
        size_t base = (size_t)(bm >> 11) * ((size_t)T_DIM * C_DIM) +
                      (size_t)col * T_DIM + (size_t)((bm & 2047) + row0);
        u16x4 o4;
        o4[0] = f2bf(v[0]); o4[1] = f2bf(v[1]); o4[2] = f2bf(v[2]); o4[3] = f2bf(v[3]);
        *(u16x4*)&C[base] = o4;
      } else {
        size_t base = (size_t)(bm + row0) * C_DIM + col;
        if (MODE == 1) {
          float* C = (float*)Cout;
#pragma unroll
          for (int r = 0; r < 4; ++r) C[base + (size_t)r * C_DIM] = v[r];
        } else {
          u16* C = (u16*)Cout;
          const float sc = (MODE == 3) ? QSCALE : 1.0f;
#pragma unroll
          for (int r = 0; r < 4; ++r) C[base + (size_t)r * C_DIM] = f2bf(v[r] * sc);
        }
      }
    }
}

// ------ causal flash attention (r15 version, measured 103 us) --------------
// KVBLK=64, 4 waves x 32 q-rows, gload_lds staging, race-free schedule
// {vm0; barrier; stage(t+1); compute(cur)}. K [64][128] + V [128][64] linear
// with both-sides XOR swizzle (unit ^= row&7).
__global__ __launch_bounds__(256, 2)
void attn_kernel(const u16* __restrict__ Qg, const u16* __restrict__ Kg,
                 const u16* __restrict__ VtG, u16* __restrict__ Y) {
  __shared__ __align__(16) u16 Klds[2][64 * 128];
  __shared__ __align__(16) u16 Vlds[2][128 * 64];
  __shared__ __align__(16) u16 Plds[4][16][72];
  const int f = blockIdx.x;
  const int pair = (f >> 3) & 7;
  const int bh = (f & 7) | ((f >> 6) << 3);   // all 8 pairs of a head on 1 XCD
  const int b = bh >> 4, h = bh & 15;
  const size_t qkbase = (size_t)b * T_DIM * C_DIM + (size_t)h * HD;
  const size_t vtbase = (size_t)b * T_DIM * C_DIM + (size_t)h * HD * T_DIM;
  const int tid = threadIdx.x, wid = tid >> 6, lane = tid & 63;
  const int l15 = lane & 15, g = lane >> 4, l7 = lane & 7;

  const int krow = (wid << 4) + (lane >> 4);
  const u16* Kge = Kg + qkbase + (size_t)krow * C_DIM + (((lane & 15) ^ (lane >> 4)) << 3);
  const u16* Kgo = Kg + qkbase + (size_t)krow * C_DIM + (((lane & 15) ^ 4 ^ (lane >> 4)) << 3);
  const int vrow = (wid << 5) + (lane >> 3);
  const u16* Vgp = VtG + vtbase + (size_t)vrow * T_DIM + (((lane & 7) ^ (lane >> 3)) << 3);

  auto stageK = [&](int buf, int kb) {
    u16* L = &Klds[buf][wid << 11];
    const u16* ge = Kge + (size_t)kb * C_DIM;
    const u16* go = Kgo + (size_t)kb * C_DIM;
    gload16(ge, L);
    gload16(go + (size_t)4 * C_DIM, L + 512);
    gload16(ge + (size_t)8 * C_DIM, L + 1024);
    gload16(go + (size_t)12 * C_DIM, L + 1536);
  };
  auto stageV = [&](int buf, int kb) {
    u16* L = &Vlds[buf][wid << 11];
    const u16* gp = Vgp + kb;
    gload16(gp, L);
    gload16(gp + (size_t)8 * T_DIM, L + 512);
    gload16(gp + (size_t)16 * T_DIM, L + 1024);
    gload16(gp + (size_t)24 * T_DIM, L + 1536);
  };

  auto process = [&](int qb) {
    __syncthreads();            // previous-process reads done before restaging
    const int rlo = qb + wid * 32;
    stageK(0, 0); stageV(0, 0);
    short8 qf[2][4];
#pragma unroll
    for (int rg = 0; rg < 2; ++rg) {
      const u16* qp = Qg + qkbase + (size_t)(rlo + rg * 16 + l15) * C_DIM + g * 8;
#pragma unroll
      for (int dc = 0; dc < 4; ++dc) qf[rg][dc] = *(const short8*)(qp + dc * 32);
    }
    f32x4 zero4 = {0.f, 0.f, 0.f, 0.f};
    f32x4 ao[2][8];
#pragma unroll
    for (int rg = 0; rg < 2; ++rg)
#pragma unroll
      for (int i = 0; i < 8; ++i) ao[rg][i] = zero4;
    float m_run[2] = {-1e30f, -1e30f};
    float l_lane[2] = {0.f, 0.f};
    const int nt = (qb >> 6) + 2;

    int cur = 0;
    for (int t = 0; t < nt; ++t) {
      const int kb = t * 64;
      wait_vm0();                     // own buf[cur] stages (and t=0 qf) landed
      __builtin_amdgcn_s_barrier();   // all waves landed; buf[cur^1] reads done
      if (t + 1 < nt) { stageK(cur ^ 1, kb + 64); stageV(cur ^ 1, kb + 64); }

      if (kb <= rlo + 31) {
        const u16* Kb_ = &Klds[cur][0];
        const u16* Vb_ = &Vlds[cur][0];
        f32x4 st[2][4];
        __builtin_amdgcn_s_setprio(1);
#pragma unroll
        for (int jt = 0; jt < 4; ++jt) {
          short8 kf[4];
#pragma unroll
          for (int dc = 0; dc < 4; ++dc)
            kf[dc] = *(const short8*)&Kb_[(jt * 16 + l15) * 128 + ((((dc << 2) | g) ^ l7) << 3)];
          f32x4 a0 = zero4, a1 = zero4;
#pragma unroll
          for (int dc = 0; dc < 4; ++dc) {
            a0 = __builtin_amdgcn_mfma_f32_16x16x32_bf16(kf[dc], qf[0][dc], a0, 0, 0, 0);
            a1 = __builtin_amdgcn_mfma_f32_16x16x32_bf16(kf[dc], qf[1][dc], a1, 0, 0, 0);
          }
          st[0][jt] = a0; st[1][jt] = a1;
        }
        __builtin_amdgcn_s_setprio(0);

        short8 pf[2][2];
#pragma unroll
        for (int rg = 0; rg < 2; ++rg) {
          const int rbase = rlo + rg * 16;
          if (kb + 63 > rbase) {
            const int qa = rbase + l15;
#pragma unroll
            for (int jt = 0; jt < 4; ++jt) {
              const int k0 = kb + jt * 16 + g * 4;
#pragma unroll
              for (int r = 0; r < 4; ++r)
                if (k0 + r > qa) st[rg][jt][r] = -3e38f;   // exp2 -> exactly 0
            }
          }

          float mxl = st[rg][0][0];
#pragma unroll
          for (int jt = 0; jt < 4; ++jt)
#pragma unroll
            for (int r = 0; r < 4; ++r) mxl = fmaxf(mxl, st[rg][jt][r]);
          if (__any(mxl > m_run[rg] + 8.0f)) {
            float mx = fmaxf(mxl, __shfl_xor(mxl, 16, 64));
            mx = fmaxf(mx, __shfl_xor(mx, 32, 64));
            float mn = fmaxf(m_run[rg], mx);
            float corr = __builtin_amdgcn_exp2f(m_run[rg] - mn);
            m_run[rg] = mn;
#pragma unroll
            for (int dc = 0; dc < 8; ++dc)
#pragma unroll
              for (int r = 0; r < 4; ++r) ao[rg][dc][r] *= corr;
            l_lane[rg] *= corr;
          }

#pragma unroll
          for (int jt = 0; jt < 4; ++jt) {
            float p0 = __builtin_amdgcn_exp2f(st[rg][jt][0] - m_run[rg]);
            float p1 = __builtin_amdgcn_exp2f(st[rg][jt][1] - m_run[rg]);
            float p2 = __builtin_amdgcn_exp2f(st[rg][jt][2] - m_run[rg]);
            float p3 = __builtin_amdgcn_exp2f(st[rg][jt][3] - m_run[rg]);
            l_lane[rg] += (p0 + p1) + (p2 + p3);
            u32x2 w;
            w[0] = cvtpk(p0, p1);
            w[1] = cvtpk(p2, p3);
            *(u32x2*)&Plds[wid][l15][jt * 16 + g * 4] = w;
          }
#pragma unroll
          for (int k2 = 0; k2 < 2; ++k2)
            pf[rg][k2] = *(const short8*)&Plds[wid][l15][k2 * 32 + g * 8];
        }

        __builtin_amdgcn_s_setprio(1);
#pragma unroll
        for (int dc = 0; dc < 8; ++dc) {
#pragma unroll
          for (int k2 = 0; k2 < 2; ++k2) {
            short8 vf = *(const short8*)&Vb_[(dc * 16 + l15) * 64 + ((((k2 << 2) | g) ^ l7) << 3)];
            ao[0][dc] = __builtin_amdgcn_mfma_f32_16x16x32_bf16(vf, pf[0][k2], ao[0][dc], 0, 0, 0);
            ao[1][dc] = __builtin_amdgcn_mfma_f32_16x16x32_bf16(vf, pf[1][k2], ao[1][dc], 0, 0, 0);
          }
        }
        __builtin_amdgcn_s_setprio(0);
      }
      cur ^= 1;
    }

#pragma unroll
    for (int rg = 0; rg < 2; ++rg) {
      float l = l_lane[rg];
      l += __shfl_xor(l, 16, 64);
      l += __shfl_xor(l, 32, 64);
      const float rcp = 1.0f / l;
      u16* yp = Y + qkbase + (size_t)(rlo + rg * 16 + l15) * C_DIM + g * 4;
#pragma unroll
      for (int dc = 0; dc < 8; ++dc) {
        u32x2 w;
        w[0] = cvtpk(ao[rg][dc][0] * rcp, ao[rg][dc][1] * rcp);
        w[1] = cvtpk(ao[rg][dc][2] * rcp, ao[rg][dc][3] * rcp);
        *(u32x2*)&yp[dc * 16] = w;
      }
    }
  };

  process(pair * 128);
  process((15 - pair) * 128);
}

extern "C" void kernel_launch(void* const* d_in, const int* in_sizes, int n_in,
                              void* d_out, int out_size, void* d_ws, size_t ws_size,
                              hipStream_t stream) {
  const float* x  = (const float*)d_in[0];
  const float* Wq = (const float*)d_in[1];
  const float* Wk = (const float*)d_in[2];
  const float* Wv = (const float*)d_in[3];
  const float* Wo = (const float*)d_in[4];
  float* out = (float*)d_out;

  const size_t SZX = (size_t)8192 * 2048;
  const size_t SZW = (size_t)2048 * 2048;
  u16* xb  = (u16*)d_ws;
  u16* Wqb = xb + SZX;
  u16* Wkb = Wqb + SZW;
  u16* Wvb = Wkb + SZW;
  u16* Wob = Wvb + SZW;
  u16* Qb  = Wob + SZW;   // Q (pre-scaled), overwritten in place by attn Y
  u16* Kb  = Qb + SZX;
  u16* Vb  = Kb + SZX;    // V^T in [b][n][t] layout

  cast_all_kernel<<<16384, 256, 0, stream>>>(x, Wq, Wk, Wv, Wo, xb, Wqb, Wkb, Wvb, Wob);

  gemm256<3><<<256, 512, 0, stream>>>(xb, Wqb, Qb);  // Q * scale*log2e
  gemm256<0><<<256, 512, 0, stream>>>(xb, Wkb, Kb);
  gemm256<2><<<256, 512, 0, stream>>>(xb, Wvb, Vb);  // V^T out

  attn_kernel<<<512, 256, 0, stream>>>(Qb, Kb, Vb, Qb);

  gemm256<1><<<256, 512, 0, stream>>>(Qb, Wob, out);
}

// Round 18
// 361.480 us; speedup vs baseline: 1.4373x; 1.1877x over previous
//
#include <hip/hip_runtime.h>
#include <stdint.h>

#define B_DIM 4
#define T_DIM 2048
#define C_DIM 2048
#define NH 16
#define HD 128

typedef unsigned short u16;
typedef __attribute__((ext_vector_type(8))) short short8;
typedef __attribute__((ext_vector_type(8))) u16 ushort8;
typedef __attribute__((ext_vector_type(4))) u16 u16x4;
typedef __attribute__((ext_vector_type(2))) uint32_t u32x2;
typedef __attribute__((ext_vector_type(4))) float f32x4;

// scale / sqrt(128) * log2(e), folded into Q-projection epilogue
#define QSCALE (0.08838834764831845f * 1.4426950408889634f)

__device__ __forceinline__ u16 f2bf(float f) {
  uint32_t u = __builtin_bit_cast(uint32_t, f);
  u = (u + 0x7FFFu + ((u >> 16) & 1u)) >> 16;
  return (u16)u;
}

__device__ __forceinline__ uint32_t cvtpk(float lo, float hi) {
  uint32_t r;
  asm("v_cvt_pk_bf16_f32 %0, %1, %2" : "=v"(r) : "v"(lo), "v"(hi));
  return r;
}

__device__ __forceinline__ void gload16(const void* g, void* l) {
  __builtin_amdgcn_global_load_lds(
      (const __attribute__((address_space(1))) void*)g,
      (__attribute__((address_space(3))) void*)l, 16, 0, 0);
}

__device__ __forceinline__ void wait_vm2() { asm volatile("s_waitcnt vmcnt(2)" ::: "memory"); }
__device__ __forceinline__ void wait_vm4() { asm volatile("s_waitcnt vmcnt(4)" ::: "memory"); }
__device__ __forceinline__ void wait_vm0() { asm volatile("s_waitcnt vmcnt(0)" ::: "memory"); }
__device__ __forceinline__ void wait_lg0() {
  asm volatile("s_waitcnt lgkmcnt(0)" ::: "memory");
  __builtin_amdgcn_sched_barrier(0);
}

// ---------------- fused cast f32 -> bf16 (x + 4 weights) ----------------
__global__ void cast_all_kernel(const float* __restrict__ x,
                                const float* __restrict__ s0, const float* __restrict__ s1,
                                const float* __restrict__ s2, const float* __restrict__ s3,
                                u16* __restrict__ xd,
                                u16* __restrict__ d0, u16* __restrict__ d1,
                                u16* __restrict__ d2, u16* __restrict__ d3) {
  const int bid = blockIdx.x;
  const float* s; u16* d; int blk;
  if (bid < 8192) { s = x; d = xd; blk = bid; }
  else {
    const int a = (bid - 8192) >> 11;
    s = a == 0 ? s0 : a == 1 ? s1 : a == 2 ? s2 : s3;
    d = a == 0 ? d0 : a == 1 ? d1 : a == 2 ? d2 : d3;
    blk = (bid - 8192) & 2047;
  }
  int i = (blk * 256 + threadIdx.x) * 8;
  f32x4 va = *(const f32x4*)(s + i);
  f32x4 vb = *(const f32x4*)(s + i + 4);
  ushort8 o;
  o[0] = f2bf(va[0]); o[1] = f2bf(va[1]); o[2] = f2bf(va[2]); o[3] = f2bf(va[3]);
  o[4] = f2bf(vb[0]); o[5] = f2bf(vb[1]); o[6] = f2bf(vb[2]); o[7] = f2bf(vb[3]);
  *(ushort8*)(d + i) = o;
}

// ============ shared 256x256 GEMM core (BK=64, 8 waves, 4 phases) ==========
#define GEMM_CORE(Aptr, Bptr, KDIM)                                            \
  const int tid = threadIdx.x, wid = tid >> 6, lane = tid & 63;                \
  const int wm = wid >> 2, wn = wid & 3;                                       \
  const int srow = (wid << 3) + (lane >> 3);                                   \
  const int scol = ((lane & 7) ^ (lane >> 3)) << 3;                            \
  const u16* Ag = Aptr + (size_t)(bm + srow) * KDIM + scol;                    \
  const u16* Bg = Bptr + (size_t)(bn + srow) * KDIM + scol;                    \
  const int sbase = wid << 9;                                                  \
  const int l15 = lane & 15;                                                   \
  const int o0 = ((lane >> 4) ^ (lane & 7)) << 3;                              \
  const int o1 = ((4 | (lane >> 4)) ^ (lane & 7)) << 3;                        \
  const int ar = ((wm << 7) + l15) << 6;                                       \
  const int br = ((wn << 6) + l15) << 6;                                       \
  f32x4 acc[8][4];                                                             \
  f32x4 zero4 = {0.f, 0.f, 0.f, 0.f};                                          \
  _Pragma("unroll") for (int i = 0; i < 8; ++i)                                \
    _Pragma("unroll") for (int n = 0; n < 4; ++n) acc[i][n] = zero4;           \
  auto stA = [&](int slot, int tc, int r0, int r1) {                           \
    gload16(Ag + (size_t)r0 * KDIM + tc, &lds[slot][(r0 << 6) + sbase]);       \
    gload16(Ag + (size_t)r1 * KDIM + tc, &lds[slot][(r1 << 6) + sbase]);       \
  };                                                                           \
  auto stB = [&](int slot, int tc, int r0, int r1) {                           \
    gload16(Bg + (size_t)r0 * KDIM + tc, &lds[slot][(r0 << 6) + sbase]);       \
    gload16(Bg + (size_t)r1 * KDIM + tc, &lds[slot][(r1 << 6) + sbase]);       \
  };                                                                           \
  stB(2, 0, 0, 64); stB(2, 0, 128, 192);                                       \
  stA(0, 0, 0, 128); stA(0, 0, 64, 192);                                       \
  short8 af[4], bf[4];                                                         \
  const int NT = KDIM >> 6;                                                    \
  _Pragma("unroll 2") for (int t = 0; t < NT; ++t) {                           \
    const int p = t & 1, q = p ^ 1;                                            \
    const int tc = ((t + 1) & (NT - 1)) << 6;                                  \
    wait_vm2();                                                                \
    __builtin_amdgcn_s_barrier();                                              \
    _Pragma("unroll") for (int i = 0; i < 4; ++i)                              \
      af[i] = *(const short8*)&lds[p][ar + (i << 10) + o0];                    \
    _Pragma("unroll") for (int n = 0; n < 4; ++n)                              \
      bf[n] = *(const short8*)&lds[2 + p][br + (n << 10) + o0];                \
    stB(2 + q, tc, 0, 64); stB(2 + q, tc, 128, 192);                           \
    __builtin_amdgcn_s_barrier();                                              \
    wait_lg0();                                                                \
    __builtin_amdgcn_s_setprio(1);                                             \
    _Pragma("unroll") for (int i = 0; i < 4; ++i)                              \
      _Pragma("unroll") for (int n = 0; n < 4; ++n)                            \
        acc[i][n] = __builtin_amdgcn_mfma_f32_16x16x32_bf16(af[i], bf[n], acc[i][n], 0, 0, 0); \
    __builtin_amdgcn_s_setprio(0);                                             \
    wait_vm4();                                                                \
    __builtin_amdgcn_s_barrier();                                              \
    _Pragma("unroll") for (int i = 0; i < 4; ++i)                              \
      af[i] = *(const short8*)&lds[p][ar + 4096 + (i << 10) + o0];             \
    stA(q, tc, 0, 128); stA(q, tc, 64, 192);                                   \
    __builtin_amdgcn_s_barrier();                                              \
    wait_lg0();                                                                \
    __builtin_amdgcn_s_setprio(1);                                             \
    _Pragma("unroll") for (int i = 0; i < 4; ++i)                              \
      _Pragma("unroll") for (int n = 0; n < 4; ++n)                            \
        acc[4 + i][n] = __builtin_amdgcn_mfma_f32_16x16x32_bf16(af[i], bf[n], acc[4 + i][n], 0, 0, 0); \
    __builtin_amdgcn_s_setprio(0);                                             \
    __builtin_amdgcn_s_barrier();                                              \
    _Pragma("unroll") for (int i = 0; i < 4; ++i)                              \
      af[i] = *(const short8*)&lds[p][ar + (i << 10) + o1];                    \
    _Pragma("unroll") for (int n = 0; n < 4; ++n)                              \
      bf[n] = *(const short8*)&lds[2 + p][br + (n << 10) + o1];                \
    __builtin_amdgcn_s_barrier();                                              \
    wait_lg0();                                                                \
    __builtin_amdgcn_s_setprio(1);                                             \
    _Pragma("unroll") for (int i = 0; i < 4; ++i)                              \
      _Pragma("unroll") for (int n = 0; n < 4; ++n)                            \
        acc[i][n] = __builtin_amdgcn_mfma_f32_16x16x32_bf16(af[i], bf[n], acc[i][n], 0, 0, 0); \
    __builtin_amdgcn_s_setprio(0);                                             \
    __builtin_amdgcn_s_barrier();                                              \
    _Pragma("unroll") for (int i = 0; i < 4; ++i)                              \
      af[i] = *(const short8*)&lds[p][ar + 4096 + (i << 10) + o1];             \
    __builtin_amdgcn_s_barrier();                                              \
    wait_lg0();                                                                \
    __builtin_amdgcn_s_setprio(1);                                             \
    _Pragma("unroll") for (int i = 0; i < 4; ++i)                              \
      _Pragma("unroll") for (int n = 0; n < 4; ++n)                            \
        acc[4 + i][n] = __builtin_amdgcn_mfma_f32_16x16x32_bf16(af[i], bf[n], acc[4 + i][n], 0, 0, 0); \
    __builtin_amdgcn_s_setprio(0);                                             \
  }                                                                            \
  wait_vm0();

// MODE 0: bf16 out. MODE 1: f32 out. MODE 2: bf16 V^T out. MODE 3: bf16*QSCALE.
template<int MODE>
__global__ __launch_bounds__(512, 2)
void gemm256(const u16* __restrict__ A, const u16* __restrict__ Bw,
             void* __restrict__ Cout) {
  __shared__ __align__(16) u16 lds[4][16384];
  const int swz = (blockIdx.x & 7) * 32 + (blockIdx.x >> 3);
  const int bm = (swz >> 3) << 8;
  const int bn = (swz & 7) << 8;

  GEMM_CORE(A, Bw, 2048)

  const int orow = (lane >> 4) << 2;
  const int ocol = lane & 15;
#pragma unroll
  for (int mi = 0; mi < 8; ++mi)
#pragma unroll
    for (int ni = 0; ni < 4; ++ni) {
      f32x4 v = acc[mi][ni];
      const int row0 = (wm << 7) + mi * 16 + orow;
      const int col = bn + (wn << 6) + ni * 16 + ocol;
      if (MODE == 2) {
        u16* C = (u16*)Cout;
        size_t base = (size_t)(bm >> 11) * ((size_t)T_DIM * C_DIM) +
                      (size_t)col * T_DIM + (size_t)((bm & 2047) + row0);
        u16x4 o;
        o[0] = f2bf(v[0]); o[1] = f2bf(v[1]); o[2] = f2bf(v[2]); o[3] = f2bf(v[3]);
        *(u16x4*)&C[base] = o;
      } else {
        size_t base = (size_t)(bm + row0) * C_DIM + col;
        if (MODE == 1) {
          float* C = (float*)Cout;
#pragma unroll
          for (int r = 0; r < 4; ++r) C[base + (size_t)r * C_DIM] = v[r];
        } else {
          u16* C = (u16*)Cout;
          const float sc = (MODE == 3) ? QSCALE : 1.0f;
#pragma unroll
          for (int r = 0; r < 4; ++r) C[base + (size_t)r * C_DIM] = f2bf(v[r] * sc);
        }
      }
    }
}

// ------ causal flash attention: 4 waves x 32 q-rows, gload_lds staging -----
// K [64][128]u16 linear + XOR swizzle (unit ^= row&7, both sides); V [128][64]
// same. Double-buffered via global_load_lds. Race-free schedule: per tile
// {vm0 (own cur-buf stages landed); barrier (all waves landed AND done reading
// the other buf); stage next into other buf; compute cur}.
__global__ __launch_bounds__(256, 2)
void attn_kernel(const u16* __restrict__ Qg, const u16* __restrict__ Kg,
                 const u16* __restrict__ VtG, u16* __restrict__ Y) {
  __shared__ __align__(16) u16 Klds[2][64 * 128];
  __shared__ __align__(16) u16 Vlds[2][128 * 64];
  __shared__ __align__(16) u16 Plds[4][16][72];
  const int f = blockIdx.x;
  const int pair = (f >> 3) & 7;
  const int bh = (f & 7) | ((f >> 6) << 3);   // all 8 pairs of a head on 1 XCD
  const int b = bh >> 4, h = bh & 15;
  const size_t qkbase = (size_t)b * T_DIM * C_DIM + (size_t)h * HD;
  const size_t vtbase = (size_t)b * T_DIM * C_DIM + (size_t)h * HD * T_DIM;
  const int tid = threadIdx.x, wid = tid >> 6, lane = tid & 63;
  const int l15 = lane & 15, g = lane >> 4, l7 = lane & 7;

  const int krow = (wid << 4) + (lane >> 4);
  const u16* Kge = Kg + qkbase + (size_t)krow * C_DIM + (((lane & 15) ^ (lane >> 4)) << 3);
  const u16* Kgo = Kg + qkbase + (size_t)krow * C_DIM + (((lane & 15) ^ 4 ^ (lane >> 4)) << 3);
  const int vrow = (wid << 5) + (lane >> 3);
  const u16* Vgp = VtG + vtbase + (size_t)vrow * T_DIM + (((lane & 7) ^ (lane >> 3)) << 3);

  auto stageK = [&](int buf, int kb) {
    u16* L = &Klds[buf][wid << 11];
    const u16* ge = Kge + (size_t)kb * C_DIM;
    const u16* go = Kgo + (size_t)kb * C_DIM;
    gload16(ge, L);
    gload16(go + (size_t)4 * C_DIM, L + 512);
    gload16(ge + (size_t)8 * C_DIM, L + 1024);
    gload16(go + (size_t)12 * C_DIM, L + 1536);
  };
  auto stageV = [&](int buf, int kb) {
    u16* L = &Vlds[buf][wid << 11];
    const u16* gp = Vgp + kb;
    gload16(gp, L);
    gload16(gp + (size_t)8 * T_DIM, L + 512);
    gload16(gp + (size_t)16 * T_DIM, L + 1024);
    gload16(gp + (size_t)24 * T_DIM, L + 1536);
  };

  auto process = [&](int qb) {
    __syncthreads();            // previous-process reads done before restaging
    const int rlo = qb + wid * 32;
    stageK(0, 0); stageV(0, 0);
    short8 qf[2][4];
#pragma unroll
    for (int rg = 0; rg < 2; ++rg) {
      const u16* qp = Qg + qkbase + (size_t)(rlo + rg * 16 + l15) * C_DIM + g * 8;
#pragma unroll
      for (int dc = 0; dc < 4; ++dc) qf[rg][dc] = *(const short8*)(qp + dc * 32);
    }
    f32x4 zero4 = {0.f, 0.f, 0.f, 0.f};
    f32x4 ao[2][8];
#pragma unroll
    for (int rg = 0; rg < 2; ++rg)
#pragma unroll
      for (int i = 0; i < 8; ++i) ao[rg][i] = zero4;
    float m_run[2] = {-1e30f, -1e30f};
    float l_lane[2] = {0.f, 0.f};
    const int nt = (qb >> 6) + 2;

    int cur = 0;
    for (int t = 0; t < nt; ++t) {
      const int kb = t * 64;
      wait_vm0();                     // own buf[cur] stages (and t=0 qf) landed
      __builtin_amdgcn_s_barrier();   // all waves landed; buf[cur^1] reads done
      if (t + 1 < nt) { stageK(cur ^ 1, kb + 64); stageV(cur ^ 1, kb + 64); }

      if (kb <= rlo + 31) {
        const u16* Kb_ = &Klds[cur][0];
        const u16* Vb_ = &Vlds[cur][0];
        f32x4 st[2][4];
        __builtin_amdgcn_s_setprio(1);
#pragma unroll
        for (int jt = 0; jt < 4; ++jt) {
          short8 kf[4];
#pragma unroll
          for (int dc = 0; dc < 4; ++dc)
            kf[dc] = *(const short8*)&Kb_[(jt * 16 + l15) * 128 + ((((dc << 2) | g) ^ l7) << 3)];
          f32x4 a0 = zero4, a1 = zero4;
#pragma unroll
          for (int dc = 0; dc < 4; ++dc) {
            a0 = __builtin_amdgcn_mfma_f32_16x16x32_bf16(kf[dc], qf[0][dc], a0, 0, 0, 0);
            a1 = __builtin_amdgcn_mfma_f32_16x16x32_bf16(kf[dc], qf[1][dc], a1, 0, 0, 0);
          }
          st[0][jt] = a0; st[1][jt] = a1;
        }
        __builtin_amdgcn_s_setprio(0);

        short8 pf[2][2];
#pragma unroll
        for (int rg = 0; rg < 2; ++rg) {
          const int rbase = rlo + rg * 16;
          if (kb + 63 > rbase) {
            const int qa = rbase + l15;
#pragma unroll
            for (int jt = 0; jt < 4; ++jt) {
              const int k0 = kb + jt * 16 + g * 4;
#pragma unroll
              for (int r = 0; r < 4; ++r)
                if (k0 + r > qa) st[rg][jt][r] = -3e38f;   // exp2 -> exactly 0
            }
          }

          float mxl = st[rg][0][0];
#pragma unroll
          for (int jt = 0; jt < 4; ++jt)
#pragma unroll
            for (int r = 0; r < 4; ++r) mxl = fmaxf(mxl, st[rg][jt][r]);
          if (__any(mxl > m_run[rg] + 8.0f)) {
            float mx = fmaxf(mxl, __shfl_xor(mxl, 16, 64));
            mx = fmaxf(mx, __shfl_xor(mx, 32, 64));
            float mn = fmaxf(m_run[rg], mx);
            float corr = __builtin_amdgcn_exp2f(m_run[rg] - mn);
            m_run[rg] = mn;
#pragma unroll
            for (int dc = 0; dc < 8; ++dc)
#pragma unroll
              for (int r = 0; r < 4; ++r) ao[rg][dc][r] *= corr;
            l_lane[rg] *= corr;
          }

#pragma unroll
          for (int jt = 0; jt < 4; ++jt) {
            float p0 = __builtin_amdgcn_exp2f(st[rg][jt][0] - m_run[rg]);
            float p1 = __builtin_amdgcn_exp2f(st[rg][jt][1] - m_run[rg]);
            float p2 = __builtin_amdgcn_exp2f(st[rg][jt][2] - m_run[rg]);
            float p3 = __builtin_amdgcn_exp2f(st[rg][jt][3] - m_run[rg]);
            l_lane[rg] += (p0 + p1) + (p2 + p3);
            u32x2 w;
            w[0] = cvtpk(p0, p1);
            w[1] = cvtpk(p2, p3);
            *(u32x2*)&Plds[wid][l15][jt * 16 + g * 4] = w;
          }
#pragma unroll
          for (int k2 = 0; k2 < 2; ++k2)
            pf[rg][k2] = *(const short8*)&Plds[wid][l15][k2 * 32 + g * 8];
        }

        __builtin_amdgcn_s_setprio(1);
#pragma unroll
        for (int dc = 0; dc < 8; ++dc) {
#pragma unroll
          for (int k2 = 0; k2 < 2; ++k2) {
            short8 vf = *(const short8*)&Vb_[(dc * 16 + l15) * 64 + ((((k2 << 2) | g) ^ l7) << 3)];
            ao[0][dc] = __builtin_amdgcn_mfma_f32_16x16x32_bf16(vf, pf[0][k2], ao[0][dc], 0, 0, 0);
            ao[1][dc] = __builtin_amdgcn_mfma_f32_16x16x32_bf16(vf, pf[1][k2], ao[1][dc], 0, 0, 0);
          }
        }
        __builtin_amdgcn_s_setprio(0);
      }
      cur ^= 1;
    }

#pragma unroll
    for (int rg = 0; rg < 2; ++rg) {
      float l = l_lane[rg];
      l += __shfl_xor(l, 16, 64);
      l += __shfl_xor(l, 32, 64);
      const float rcp = 1.0f / l;
      u16* yp = Y + qkbase + (size_t)(rlo + rg * 16 + l15) * C_DIM + g * 4;
#pragma unroll
      for (int dc = 0; dc < 8; ++dc) {
        u32x2 w;
        w[0] = cvtpk(ao[rg][dc][0] * rcp, ao[rg][dc][1] * rcp);
        w[1] = cvtpk(ao[rg][dc][2] * rcp, ao[rg][dc][3] * rcp);
        *(u32x2*)&yp[dc * 16] = w;
      }
    }
  };

  process(pair * 128);
  process((15 - pair) * 128);
}

extern "C" void kernel_launch(void* const* d_in, const int* in_sizes, int n_in,
                              void* d_out, int out_size, void* d_ws, size_t ws_size,
                              hipStream_t stream) {
  const float* x  = (const float*)d_in[0];
  const float* Wq = (const float*)d_in[1];
  const float* Wk = (const float*)d_in[2];
  const float* Wv = (const float*)d_in[3];
  const float* Wo = (const float*)d_in[4];
  float* out = (float*)d_out;

  const size_t SZX = (size_t)8192 * 2048;
  const size_t SZW = (size_t)2048 * 2048;
  u16* xb  = (u16*)d_ws;
  u16* Wqb = xb + SZX;
  u16* Wkb = Wqb + SZW;
  u16* Wvb = Wkb + SZW;
  u16* Wob = Wvb + SZW;
  u16* Qb  = Wob + SZW;   // Q (pre-scaled), overwritten in place by attn Y
  u16* Kb  = Qb + SZX;
  u16* Vb  = Kb + SZX;    // V^T in [b][n][t] layout

  cast_all_kernel<<<16384, 256, 0, stream>>>(x, Wq, Wk, Wv, Wo, xb, Wqb, Wkb, Wvb, Wob);

  gemm256<3><<<256, 512, 0, stream>>>(xb, Wqb, Qb);  // Q * scale*log2e
  gemm256<0><<<256, 512, 0, stream>>>(xb, Wkb, Kb);
  gemm256<2><<<256, 512, 0, stream>>>(xb, Wvb, Vb);  // V^T out

  attn_kernel<<<512, 256, 0, stream>>>(Qb, Kb, Vb, Qb);

  gemm256<1><<<256, 512, 0, stream>>>(Qb, Wob, out);
}

// Round 19
// 359.737 us; speedup vs baseline: 1.4443x; 1.0048x over previous
//
#include <hip/hip_runtime.h>
#include <stdint.h>

#define B_DIM 4
#define T_DIM 2048
#define C_DIM 2048
#define NH 16
#define HD 128

typedef unsigned short u16;
typedef __attribute__((ext_vector_type(8))) short short8;
typedef __attribute__((ext_vector_type(8))) u16 ushort8;
typedef __attribute__((ext_vector_type(4))) u16 u16x4;
typedef __attribute__((ext_vector_type(2))) uint32_t u32x2;
typedef __attribute__((ext_vector_type(4))) float f32x4;

// scale / sqrt(128) * log2(e), folded into Q-projection epilogue
#define QSCALE (0.08838834764831845f * 1.4426950408889634f)

__device__ __forceinline__ u16 f2bf(float f) {
  uint32_t u = __builtin_bit_cast(uint32_t, f);
  u = (u + 0x7FFFu + ((u >> 16) & 1u)) >> 16;
  return (u16)u;
}

__device__ __forceinline__ uint32_t cvtpk(float lo, float hi) {
  uint32_t r;
  asm("v_cvt_pk_bf16_f32 %0, %1, %2" : "=v"(r) : "v"(lo), "v"(hi));
  return r;
}

__device__ __forceinline__ void gload16(const void* g, void* l) {
  __builtin_amdgcn_global_load_lds(
      (const __attribute__((address_space(1))) void*)g,
      (__attribute__((address_space(3))) void*)l, 16, 0, 0);
}

__device__ __forceinline__ void wait_vm2() { asm volatile("s_waitcnt vmcnt(2)" ::: "memory"); }
__device__ __forceinline__ void wait_vm4() { asm volatile("s_waitcnt vmcnt(4)" ::: "memory"); }
__device__ __forceinline__ void wait_vm0() { asm volatile("s_waitcnt vmcnt(0)" ::: "memory"); }
__device__ __forceinline__ void wait_lg0() {
  asm volatile("s_waitcnt lgkmcnt(0)" ::: "memory");
  __builtin_amdgcn_sched_barrier(0);
}

// ---------------- fused cast f32 -> bf16 (x + 4 weights) ----------------
__global__ void cast_all_kernel(const float* __restrict__ x,
                                const float* __restrict__ s0, const float* __restrict__ s1,
                                const float* __restrict__ s2, const float* __restrict__ s3,
                                u16* __restrict__ xd,
                                u16* __restrict__ d0, u16* __restrict__ d1,
                                u16* __restrict__ d2, u16* __restrict__ d3) {
  const int bid = blockIdx.x;
  const float* s; u16* d; int blk;
  if (bid < 8192) { s = x; d = xd; blk = bid; }
  else {
    const int a = (bid - 8192) >> 11;
    s = a == 0 ? s0 : a == 1 ? s1 : a == 2 ? s2 : s3;
    d = a == 0 ? d0 : a == 1 ? d1 : a == 2 ? d2 : d3;
    blk = (bid - 8192) & 2047;
  }
  int i = (blk * 256 + threadIdx.x) * 8;
  f32x4 va = *(const f32x4*)(s + i);
  f32x4 vb = *(const f32x4*)(s + i + 4);
  ushort8 o;
  o[0] = f2bf(va[0]); o[1] = f2bf(va[1]); o[2] = f2bf(va[2]); o[3] = f2bf(va[3]);
  o[4] = f2bf(vb[0]); o[5] = f2bf(vb[1]); o[6] = f2bf(vb[2]); o[7] = f2bf(vb[3]);
  *(ushort8*)(d + i) = o;
}

// ============ shared 256x256 GEMM core (BK=64, 8 waves, 4 phases) ==========
// 4 barriers/K-tile (leading barrier per phase only). Invariant: each phase's
// barrier sits AFTER every wave's own vm-wait, so passing it implies all
// waves' staged data for this phase is in LDS. Trailing barriers removed —
// within a tile phases only read slots {p,2+p} and stage into {q,2+q}
// (disjoint), so no intra-tile write-read hazard exists; waves may drift,
// overlapping one wave's MFMA with another's ds_reads on the same SIMD.
#define GEMM_CORE(Aptr, Bptr, KDIM)                                            \
  const int tid = threadIdx.x, wid = tid >> 6, lane = tid & 63;                \
  const int wm = wid >> 2, wn = wid & 3;                                       \
  const int srow = (wid << 3) + (lane >> 3);                                   \
  const int scol = ((lane & 7) ^ (lane >> 3)) << 3;                            \
  const u16* Ag = Aptr + (size_t)(bm + srow) * KDIM + scol;                    \
  const u16* Bg = Bptr + (size_t)(bn + srow) * KDIM + scol;                    \
  const int sbase = wid << 9;                                                  \
  const int l15 = lane & 15;                                                   \
  const int o0 = ((lane >> 4) ^ (lane & 7)) << 3;                              \
  const int o1 = ((4 | (lane >> 4)) ^ (lane & 7)) << 3;                        \
  const int ar = ((wm << 7) + l15) << 6;                                       \
  const int br = ((wn << 6) + l15) << 6;                                       \
  f32x4 acc[8][4];                                                             \
  f32x4 zero4 = {0.f, 0.f, 0.f, 0.f};                                          \
  _Pragma("unroll") for (int i = 0; i < 8; ++i)                                \
    _Pragma("unroll") for (int n = 0; n < 4; ++n) acc[i][n] = zero4;           \
  auto stA = [&](int slot, int tc, int r0, int r1) {                           \
    gload16(Ag + (size_t)r0 * KDIM + tc, &lds[slot][(r0 << 6) + sbase]);       \
    gload16(Ag + (size_t)r1 * KDIM + tc, &lds[slot][(r1 << 6) + sbase]);       \
  };                                                                           \
  auto stB = [&](int slot, int tc, int r0, int r1) {                           \
    gload16(Bg + (size_t)r0 * KDIM + tc, &lds[slot][(r0 << 6) + sbase]);       \
    gload16(Bg + (size_t)r1 * KDIM + tc, &lds[slot][(r1 << 6) + sbase]);       \
  };                                                                           \
  stB(2, 0, 0, 64); stB(2, 0, 128, 192);                                       \
  stA(0, 0, 0, 128); stA(0, 0, 64, 192);                                       \
  short8 af[4], bf[4];                                                         \
  const int NT = KDIM >> 6;                                                    \
  _Pragma("unroll 2") for (int t = 0; t < NT; ++t) {                           \
    const int p = t & 1, q = p ^ 1;                                            \
    const int tc = ((t + 1) & (NT - 1)) << 6;                                  \
    /* P1: kk0, acc rows 0-3; stage B(t+1) */                                  \
    wait_vm2();                                                                \
    __builtin_amdgcn_s_barrier();                                              \
    _Pragma("unroll") for (int i = 0; i < 4; ++i)                              \
      af[i] = *(const short8*)&lds[p][ar + (i << 10) + o0];                    \
    _Pragma("unroll") for (int n = 0; n < 4; ++n)                              \
      bf[n] = *(const short8*)&lds[2 + p][br + (n << 10) + o0];                \
    stB(2 + q, tc, 0, 64); stB(2 + q, tc, 128, 192);                           \
    wait_lg0();                                                                \
    __builtin_amdgcn_s_setprio(1);                                             \
    _Pragma("unroll") for (int i = 0; i < 4; ++i)                              \
      _Pragma("unroll") for (int n = 0; n < 4; ++n)                            \
        acc[i][n] = __builtin_amdgcn_mfma_f32_16x16x32_bf16(af[i], bf[n], acc[i][n], 0, 0, 0); \
    __builtin_amdgcn_s_setprio(0);                                             \
    /* P2: kk0, acc rows 4-7; stage A(t+1) */                                  \
    wait_vm4();                                                                \
    __builtin_amdgcn_s_barrier();                                              \
    _Pragma("unroll") for (int i = 0; i < 4; ++i)                              \
      af[i] = *(const short8*)&lds[p][ar + 4096 + (i << 10) + o0];             \
    stA(q, tc, 0, 128); stA(q, tc, 64, 192);                                   \
    wait_lg0();                                                                \
    __builtin_amdgcn_s_setprio(1);                                             \
    _Pragma("unroll") for (int i = 0; i < 4; ++i)                              \
      _Pragma("unroll") for (int n = 0; n < 4; ++n)                            \
        acc[4 + i][n] = __builtin_amdgcn_mfma_f32_16x16x32_bf16(af[i], bf[n], acc[4 + i][n], 0, 0, 0); \
    __builtin_amdgcn_s_setprio(0);                                             \
    /* P3: kk1, acc rows 0-3 */                                                \
    __builtin_amdgcn_s_barrier();                                              \
    _Pragma("unroll") for (int i = 0; i < 4; ++i)                              \
      af[i] = *(const short8*)&lds[p][ar + (i << 10) + o1];                    \
    _Pragma("unroll") for (int n = 0; n < 4; ++n)                              \
      bf[n] = *(const short8*)&lds[2 + p][br + (n << 10) + o1];                \
    wait_lg0();                                                                \
    __builtin_amdgcn_s_setprio(1);                                             \
    _Pragma("unroll") for (int i = 0; i < 4; ++i)                              \
      _Pragma("unroll") for (int n = 0; n < 4; ++n)                            \
        acc[i][n] = __builtin_amdgcn_mfma_f32_16x16x32_bf16(af[i], bf[n], acc[i][n], 0, 0, 0); \
    __builtin_amdgcn_s_setprio(0);                                             \
    /* P4: kk1, acc rows 4-7 */                                                \
    __builtin_amdgcn_s_barrier();                                              \
    _Pragma("unroll") for (int i = 0; i < 4; ++i)                              \
      af[i] = *(const short8*)&lds[p][ar + 4096 + (i << 10) + o1];             \
    wait_lg0();                                                                \
    __builtin_amdgcn_s_setprio(1);                                             \
    _Pragma("unroll") for (int i = 0; i < 4; ++i)                              \
      _Pragma("unroll") for (int n = 0; n < 4; ++n)                            \
        acc[4 + i][n] = __builtin_amdgcn_mfma_f32_16x16x32_bf16(af[i], bf[n], acc[4 + i][n], 0, 0, 0); \
    __builtin_amdgcn_s_setprio(0);                                             \
  }                                                                            \
  wait_vm0();

// MODE 0: bf16 out. MODE 1: f32 out. MODE 2: bf16 V^T out. MODE 3: bf16*QSCALE.
template<int MODE>
__global__ __launch_bounds__(512, 2)
void gemm256(const u16* __restrict__ A, const u16* __restrict__ Bw,
             void* __restrict__ Cout) {
  __shared__ __align__(16) u16 lds[4][16384];
  const int swz = (blockIdx.x & 7) * 32 + (blockIdx.x >> 3);
  const int bm = (swz >> 3) << 8;
  const int bn = (swz & 7) << 8;

  GEMM_CORE(A, Bw, 2048)

  const int orow = (lane >> 4) << 2;
  const int ocol = lane & 15;
#pragma unroll
  for (int mi = 0; mi < 8; ++mi)
#pragma unroll
    for (int ni = 0; ni < 4; ++ni) {
      f32x4 v = acc[mi][ni];
      const int row0 = (wm << 7) + mi * 16 + orow;
      const int col = bn + (wn << 6) + ni * 16 + ocol;
      if (MODE == 2) {
        u16* C = (u16*)Cout;
        size_t base = (size_t)(bm >> 11) * ((size_t)T_DIM * C_DIM) +
                      (size_t)col * T_DIM + (size_t)((bm & 2047) + row0);
        u16x4 o;
        o[0] = f2bf(v[0]); o[1] = f2bf(v[1]); o[2] = f2bf(v[2]); o[3] = f2bf(v[3]);
        *(u16x4*)&C[base] = o;
      } else {
        size_t base = (size_t)(bm + row0) * C_DIM + col;
        if (MODE == 1) {
          float* C = (float*)Cout;
#pragma unroll
          for (int r = 0; r < 4; ++r) C[base + (size_t)r * C_DIM] = v[r];
        } else {
          u16* C = (u16*)Cout;
          const float sc = (MODE == 3) ? QSCALE : 1.0f;
#pragma unroll
          for (int r = 0; r < 4; ++r) C[base + (size_t)r * C_DIM] = f2bf(v[r] * sc);
        }
      }
    }
}

// ------ causal flash attention: 4 waves x 32 q-rows, gload_lds staging -----
// (r15/r18 version, measured 103 us)
__global__ __launch_bounds__(256, 2)
void attn_kernel(const u16* __restrict__ Qg, const u16* __restrict__ Kg,
                 const u16* __restrict__ VtG, u16* __restrict__ Y) {
  __shared__ __align__(16) u16 Klds[2][64 * 128];
  __shared__ __align__(16) u16 Vlds[2][128 * 64];
  __shared__ __align__(16) u16 Plds[4][16][72];
  const int f = blockIdx.x;
  const int pair = (f >> 3) & 7;
  const int bh = (f & 7) | ((f >> 6) << 3);   // all 8 pairs of a head on 1 XCD
  const int b = bh >> 4, h = bh & 15;
  const size_t qkbase = (size_t)b * T_DIM * C_DIM + (size_t)h * HD;
  const size_t vtbase = (size_t)b * T_DIM * C_DIM + (size_t)h * HD * T_DIM;
  const int tid = threadIdx.x, wid = tid >> 6, lane = tid & 63;
  const int l15 = lane & 15, g = lane >> 4, l7 = lane & 7;

  const int krow = (wid << 4) + (lane >> 4);
  const u16* Kge = Kg + qkbase + (size_t)krow * C_DIM + (((lane & 15) ^ (lane >> 4)) << 3);
  const u16* Kgo = Kg + qkbase + (size_t)krow * C_DIM + (((lane & 15) ^ 4 ^ (lane >> 4)) << 3);
  const int vrow = (wid << 5) + (lane >> 3);
  const u16* Vgp = VtG + vtbase + (size_t)vrow * T_DIM + (((lane & 7) ^ (lane >> 3)) << 3);

  auto stageK = [&](int buf, int kb) {
    u16* L = &Klds[buf][wid << 11];
    const u16* ge = Kge + (size_t)kb * C_DIM;
    const u16* go = Kgo + (size_t)kb * C_DIM;
    gload16(ge, L);
    gload16(go + (size_t)4 * C_DIM, L + 512);
    gload16(ge + (size_t)8 * C_DIM, L + 1024);
    gload16(go + (size_t)12 * C_DIM, L + 1536);
  };
  auto stageV = [&](int buf, int kb) {
    u16* L = &Vlds[buf][wid << 11];
    const u16* gp = Vgp + kb;
    gload16(gp, L);
    gload16(gp + (size_t)8 * T_DIM, L + 512);
    gload16(gp + (size_t)16 * T_DIM, L + 1024);
    gload16(gp + (size_t)24 * T_DIM, L + 1536);
  };

  auto process = [&](int qb) {
    __syncthreads();            // previous-process reads done before restaging
    const int rlo = qb + wid * 32;
    stageK(0, 0); stageV(0, 0);
    short8 qf[2][4];
#pragma unroll
    for (int rg = 0; rg < 2; ++rg) {
      const u16* qp = Qg + qkbase + (size_t)(rlo + rg * 16 + l15) * C_DIM + g * 8;
#pragma unroll
      for (int dc = 0; dc < 4; ++dc) qf[rg][dc] = *(const short8*)(qp + dc * 32);
    }
    f32x4 zero4 = {0.f, 0.f, 0.f, 0.f};
    f32x4 ao[2][8];
#pragma unroll
    for (int rg = 0; rg < 2; ++rg)
#pragma unroll
      for (int i = 0; i < 8; ++i) ao[rg][i] = zero4;
    float m_run[2] = {-1e30f, -1e30f};
    float l_lane[2] = {0.f, 0.f};
    const int nt = (qb >> 6) + 2;

    int cur = 0;
    for (int t = 0; t < nt; ++t) {
      const int kb = t * 64;
      wait_vm0();                     // own buf[cur] stages (and t=0 qf) landed
      __builtin_amdgcn_s_barrier();   // all waves landed; buf[cur^1] reads done
      if (t + 1 < nt) { stageK(cur ^ 1, kb + 64); stageV(cur ^ 1, kb + 64); }

      if (kb <= rlo + 31) {
        const u16* Kb_ = &Klds[cur][0];
        const u16* Vb_ = &Vlds[cur][0];
        f32x4 st[2][4];
        __builtin_amdgcn_s_setprio(1);
#pragma unroll
        for (int jt = 0; jt < 4; ++jt) {
          short8 kf[4];
#pragma unroll
          for (int dc = 0; dc < 4; ++dc)
            kf[dc] = *(const short8*)&Kb_[(jt * 16 + l15) * 128 + ((((dc << 2) | g) ^ l7) << 3)];
          f32x4 a0 = zero4, a1 = zero4;
#pragma unroll
          for (int dc = 0; dc < 4; ++dc) {
            a0 = __builtin_amdgcn_mfma_f32_16x16x32_bf16(kf[dc], qf[0][dc], a0, 0, 0, 0);
            a1 = __builtin_amdgcn_mfma_f32_16x16x32_bf16(kf[dc], qf[1][dc], a1, 0, 0, 0);
          }
          st[0][jt] = a0; st[1][jt] = a1;
        }
        __builtin_amdgcn_s_setprio(0);

        short8 pf[2][2];
#pragma unroll
        for (int rg = 0; rg < 2; ++rg) {
          const int rbase = rlo + rg * 16;
          if (kb + 63 > rbase) {
            const int qa = rbase + l15;
#pragma unroll
            for (int jt = 0; jt < 4; ++jt) {
              const int k0 = kb + jt * 16 + g * 4;
#pragma unroll
              for (int r = 0; r < 4; ++r)
                if (k0 + r > qa) st[rg][jt][r] = -3e38f;   // exp2 -> exactly 0
            }
          }

          float mxl = st[rg][0][0];
#pragma unroll
          for (int jt = 0; jt < 4; ++jt)
#pragma unroll
            for (int r = 0; r < 4; ++r) mxl = fmaxf(mxl, st[rg][jt][r]);
          if (__any(mxl > m_run[rg] + 8.0f)) {
            float mx = fmaxf(mxl, __shfl_xor(mxl, 16, 64));
            mx = fmaxf(mx, __shfl_xor(mx, 32, 64));
            float mn = fmaxf(m_run[rg], mx);
            float corr = __builtin_amdgcn_exp2f(m_run[rg] - mn);
            m_run[rg] = mn;
#pragma unroll
            for (int dc = 0; dc < 8; ++dc)
#pragma unroll
              for (int r = 0; r < 4; ++r) ao[rg][dc][r] *= corr;
            l_lane[rg] *= corr;
          }

#pragma unroll
          for (int jt = 0; jt < 4; ++jt) {
            float p0 = __builtin_amdgcn_exp2f(st[rg][jt][0] - m_run[rg]);
            float p1 = __builtin_amdgcn_exp2f(st[rg][jt][1] - m_run[rg]);
            float p2 = __builtin_amdgcn_exp2f(st[rg][jt][2] - m_run[rg]);
            float p3 = __builtin_amdgcn_exp2f(st[rg][jt][3] - m_run[rg]);
            l_lane[rg] += (p0 + p1) + (p2 + p3);
            u32x2 w;
            w[0] = cvtpk(p0, p1);
            w[1] = cvtpk(p2, p3);
            *(u32x2*)&Plds[wid][l15][jt * 16 + g * 4] = w;
          }
#pragma unroll
          for (int k2 = 0; k2 < 2; ++k2)
            pf[rg][k2] = *(const short8*)&Plds[wid][l15][k2 * 32 + g * 8];
        }

        __builtin_amdgcn_s_setprio(1);
#pragma unroll
        for (int dc = 0; dc < 8; ++dc) {
#pragma unroll
          for (int k2 = 0; k2 < 2; ++k2) {
            short8 vf = *(const short8*)&Vb_[(dc * 16 + l15) * 64 + ((((k2 << 2) | g) ^ l7) << 3)];
            ao[0][dc] = __builtin_amdgcn_mfma_f32_16x16x32_bf16(vf, pf[0][k2], ao[0][dc], 0, 0, 0);
            ao[1][dc] = __builtin_amdgcn_mfma_f32_16x16x32_bf16(vf, pf[1][k2], ao[1][dc], 0, 0, 0);
          }
        }
        __builtin_amdgcn_s_setprio(0);
      }
      cur ^= 1;
    }

#pragma unroll
    for (int rg = 0; rg < 2; ++rg) {
      float l = l_lane[rg];
      l += __shfl_xor(l, 16, 64);
      l += __shfl_xor(l, 32, 64);
      const float rcp = 1.0f / l;
      u16* yp = Y + qkbase + (size_t)(rlo + rg * 16 + l15) * C_DIM + g * 4;
#pragma unroll
      for (int dc = 0; dc < 8; ++dc) {
        u32x2 w;
        w[0] = cvtpk(ao[rg][dc][0] * rcp, ao[rg][dc][1] * rcp);
        w[1] = cvtpk(ao[rg][dc][2] * rcp, ao[rg][dc][3] * rcp);
        *(u32x2*)&yp[dc * 16] = w;
      }
    }
  };

  process(pair * 128);
  process((15 - pair) * 128);
}

extern "C" void kernel_launch(void* const* d_in, const int* in_sizes, int n_in,
                              void* d_out, int out_size, void* d_ws, size_t ws_size,
                              hipStream_t stream) {
  const float* x  = (const float*)d_in[0];
  const float* Wq = (const float*)d_in[1];
  const float* Wk = (const float*)d_in[2];
  const float* Wv = (const float*)d_in[3];
  const float* Wo = (const float*)d_in[4];
  float* out = (float*)d_out;

  const size_t SZX = (size_t)8192 * 2048;
  const size_t SZW = (size_t)2048 * 2048;
  u16* xb  = (u16*)d_ws;
  u16* Wqb = xb + SZX;
  u16* Wkb = Wqb + SZW;
  u16* Wvb = Wkb + SZW;
  u16* Wob = Wvb + SZW;
  u16* Qb  = Wob + SZW;   // Q (pre-scaled), overwritten in place by attn Y
  u16* Kb  = Qb + SZX;
  u16* Vb  = Kb + SZX;    // V^T in [b][n][t] layout

  cast_all_kernel<<<16384, 256, 0, stream>>>(x, Wq, Wk, Wv, Wo, xb, Wqb, Wkb, Wvb, Wob);

  gemm256<3><<<256, 512, 0, stream>>>(xb, Wqb, Qb);  // Q * scale*log2e
  gemm256<0><<<256, 512, 0, stream>>>(xb, Wkb, Kb);
  gemm256<2><<<256, 512, 0, stream>>>(xb, Wvb, Vb);  // V^T out

  attn_kernel<<<512, 256, 0, stream>>>(Qb, Kb, Vb, Qb);

  gemm256<1><<<256, 512, 0, stream>>>(Qb, Wob, out);
}

// Round 20
// 353.335 us; speedup vs baseline: 1.4704x; 1.0181x over previous
//
#include <hip/hip_runtime.h>
#include <stdint.h>

#define B_DIM 4
#define T_DIM 2048
#define C_DIM 2048
#define NH 16
#define HD 128

typedef unsigned short u16;
typedef __attribute__((ext_vector_type(8))) short short8;
typedef __attribute__((ext_vector_type(8))) u16 ushort8;
typedef __attribute__((ext_vector_type(4))) u16 u16x4;
typedef __attribute__((ext_vector_type(2))) uint32_t u32x2;
typedef __attribute__((ext_vector_type(4))) float f32x4;

// scale / sqrt(128) * log2(e), folded into Q-projection epilogue
#define QSCALE (0.08838834764831845f * 1.4426950408889634f)

__device__ __forceinline__ u16 f2bf(float f) {
  uint32_t u = __builtin_bit_cast(uint32_t, f);
  u = (u + 0x7FFFu + ((u >> 16) & 1u)) >> 16;
  return (u16)u;
}

__device__ __forceinline__ uint32_t cvtpk(float lo, float hi) {
  uint32_t r;
  asm("v_cvt_pk_bf16_f32 %0, %1, %2" : "=v"(r) : "v"(lo), "v"(hi));
  return r;
}

__device__ __forceinline__ void gload16(const void* g, void* l) {
  __builtin_amdgcn_global_load_lds(
      (const __attribute__((address_space(1))) void*)g,
      (__attribute__((address_space(3))) void*)l, 16, 0, 0);
}

__device__ __forceinline__ void wait_vm2() { asm volatile("s_waitcnt vmcnt(2)" ::: "memory"); }
__device__ __forceinline__ void wait_vm4() { asm volatile("s_waitcnt vmcnt(4)" ::: "memory"); }
__device__ __forceinline__ void wait_vm0() { asm volatile("s_waitcnt vmcnt(0)" ::: "memory"); }
__device__ __forceinline__ void wait_lg0() {
  asm volatile("s_waitcnt lgkmcnt(0)" ::: "memory");
  __builtin_amdgcn_sched_barrier(0);
}

// ---------------- fused cast f32 -> bf16 (x + 4 weights) ----------------
__global__ void cast_all_kernel(const float* __restrict__ x,
                                const float* __restrict__ s0, const float* __restrict__ s1,
                                const float* __restrict__ s2, const float* __restrict__ s3,
                                u16* __restrict__ xd,
                                u16* __restrict__ d0, u16* __restrict__ d1,
                                u16* __restrict__ d2, u16* __restrict__ d3) {
  const int bid = blockIdx.x;
  const float* s; u16* d; int blk;
  if (bid < 8192) { s = x; d = xd; blk = bid; }
  else {
    const int a = (bid - 8192) >> 11;
    s = a == 0 ? s0 : a == 1 ? s1 : a == 2 ? s2 : s3;
    d = a == 0 ? d0 : a == 1 ? d1 : a == 2 ? d2 : d3;
    blk = (bid - 8192) & 2047;
  }
  int i = (blk * 256 + threadIdx.x) * 8;
  f32x4 va = *(const f32x4*)(s + i);
  f32x4 vb = *(const f32x4*)(s + i + 4);
  ushort8 o;
  o[0] = f2bf(va[0]); o[1] = f2bf(va[1]); o[2] = f2bf(va[2]); o[3] = f2bf(va[3]);
  o[4] = f2bf(vb[0]); o[5] = f2bf(vb[1]); o[6] = f2bf(vb[2]); o[7] = f2bf(vb[3]);
  *(ushort8*)(d + i) = o;
}

// ============ shared 256x256 GEMM core (BK=64, 8 waves, 4 phases) ==========
// 4 barriers/K-tile (leading barrier per phase only; see r19 proof).
#define GEMM_CORE(Aptr, Bptr, KDIM)                                            \
  const int tid = threadIdx.x, wid = tid >> 6, lane = tid & 63;                \
  const int wm = wid >> 2, wn = wid & 3;                                       \
  const int srow = (wid << 3) + (lane >> 3);                                   \
  const int scol = ((lane & 7) ^ (lane >> 3)) << 3;                            \
  const u16* Ag = Aptr + (size_t)(bm + srow) * KDIM + scol;                    \
  const u16* Bg = Bptr + (size_t)(bn + srow) * KDIM + scol;                    \
  const int sbase = wid << 9;                                                  \
  const int l15 = lane & 15;                                                   \
  const int o0 = ((lane >> 4) ^ (lane & 7)) << 3;                              \
  const int o1 = ((4 | (lane >> 4)) ^ (lane & 7)) << 3;                        \
  const int ar = ((wm << 7) + l15) << 6;                                       \
  const int br = ((wn << 6) + l15) << 6;                                       \
  f32x4 acc[8][4];                                                             \
  f32x4 zero4 = {0.f, 0.f, 0.f, 0.f};                                          \
  _Pragma("unroll") for (int i = 0; i < 8; ++i)                                \
    _Pragma("unroll") for (int n = 0; n < 4; ++n) acc[i][n] = zero4;           \
  auto stA = [&](int slot, int tc, int r0, int r1) {                           \
    gload16(Ag + (size_t)r0 * KDIM + tc, &lds[slot][(r0 << 6) + sbase]);       \
    gload16(Ag + (size_t)r1 * KDIM + tc, &lds[slot][(r1 << 6) + sbase]);       \
  };                                                                           \
  auto stB = [&](int slot, int tc, int r0, int r1) {                           \
    gload16(Bg + (size_t)r0 * KDIM + tc, &lds[slot][(r0 << 6) + sbase]);       \
    gload16(Bg + (size_t)r1 * KDIM + tc, &lds[slot][(r1 << 6) + sbase]);       \
  };                                                                           \
  stB(2, 0, 0, 64); stB(2, 0, 128, 192);                                       \
  stA(0, 0, 0, 128); stA(0, 0, 64, 192);                                       \
  short8 af[4], bf[4];                                                         \
  const int NT = KDIM >> 6;                                                    \
  _Pragma("unroll 2") for (int t = 0; t < NT; ++t) {                           \
    const int p = t & 1, q = p ^ 1;                                            \
    const int tc = ((t + 1) & (NT - 1)) << 6;                                  \
    /* P1: kk0, acc rows 0-3; stage B(t+1) */                                  \
    wait_vm2();                                                                \
    __builtin_amdgcn_s_barrier();                                              \
    _Pragma("unroll") for (int i = 0; i < 4; ++i)                              \
      af[i] = *(const short8*)&lds[p][ar + (i << 10) + o0];                    \
    _Pragma("unroll") for (int n = 0; n < 4; ++n)                              \
      bf[n] = *(const short8*)&lds[2 + p][br + (n << 10) + o0];                \
    stB(2 + q, tc, 0, 64); stB(2 + q, tc, 128, 192);                           \
    wait_lg0();                                                                \
    __builtin_amdgcn_s_setprio(1);                                             \
    _Pragma("unroll") for (int i = 0; i < 4; ++i)                              \
      _Pragma("unroll") for (int n = 0; n < 4; ++n)                            \
        acc[i][n] = __builtin_amdgcn_mfma_f32_16x16x32_bf16(af[i], bf[n], acc[i][n], 0, 0, 0); \
    __builtin_amdgcn_s_setprio(0);                                             \
    /* P2: kk0, acc rows 4-7; stage A(t+1) */                                  \
    wait_vm4();                                                                \
    __builtin_amdgcn_s_barrier();                                              \
    _Pragma("unroll") for (int i = 0; i < 4; ++i)                              \
      af[i] = *(const short8*)&lds[p][ar + 4096 + (i << 10) + o0];             \
    stA(q, tc, 0, 128); stA(q, tc, 64, 192);                                   \
    wait_lg0();                                                                \
    __builtin_amdgcn_s_setprio(1);                                             \
    _Pragma("unroll") for (int i = 0; i < 4; ++i)                              \
      _Pragma("unroll") for (int n = 0; n < 4; ++n)                            \
        acc[4 + i][n] = __builtin_amdgcn_mfma_f32_16x16x32_bf16(af[i], bf[n], acc[4 + i][n], 0, 0, 0); \
    __builtin_amdgcn_s_setprio(0);                                             \
    /* P3: kk1, acc rows 0-3 */                                                \
    __builtin_amdgcn_s_barrier();                                              \
    _Pragma("unroll") for (int i = 0; i < 4; ++i)                              \
      af[i] = *(const short8*)&lds[p][ar + (i << 10) + o1];                    \
    _Pragma("unroll") for (int n = 0; n < 4; ++n)                              \
      bf[n] = *(const short8*)&lds[2 + p][br + (n << 10) + o1];                \
    wait_lg0();                                                                \
    __builtin_amdgcn_s_setprio(1);                                             \
    _Pragma("unroll") for (int i = 0; i < 4; ++i)                              \
      _Pragma("unroll") for (int n = 0; n < 4; ++n)                            \
        acc[i][n] = __builtin_amdgcn_mfma_f32_16x16x32_bf16(af[i], bf[n], acc[i][n], 0, 0, 0); \
    __builtin_amdgcn_s_setprio(0);                                             \
    /* P4: kk1, acc rows 4-7 */                                                \
    __builtin_amdgcn_s_barrier();                                              \
    _Pragma("unroll") for (int i = 0; i < 4; ++i)                              \
      af[i] = *(const short8*)&lds[p][ar + 4096 + (i << 10) + o1];             \
    wait_lg0();                                                                \
    __builtin_amdgcn_s_setprio(1);                                             \
    _Pragma("unroll") for (int i = 0; i < 4; ++i)                              \
      _Pragma("unroll") for (int n = 0; n < 4; ++n)                            \
        acc[4 + i][n] = __builtin_amdgcn_mfma_f32_16x16x32_bf16(af[i], bf[n], acc[4 + i][n], 0, 0, 0); \
    __builtin_amdgcn_s_setprio(0);                                             \
  }                                                                            \
  wait_vm0();

// MODE 0: bf16 out. MODE 1: f32 out. MODE 2: bf16 V^T out. MODE 3: bf16*QSCALE.
template<int MODE>
__global__ __launch_bounds__(512, 1)
void gemm256(const u16* __restrict__ A, const u16* __restrict__ Bw,
             void* __restrict__ Cout) {
  __shared__ __align__(16) u16 lds[4][16384];
  const int swz = (blockIdx.x & 7) * 32 + (blockIdx.x >> 3);
  const int bm = (swz >> 3) << 8;
  const int bn = (swz & 7) << 8;

  GEMM_CORE(A, Bw, 2048)

  const int orow = (lane >> 4) << 2;
  const int ocol = lane & 15;
#pragma unroll
  for (int mi = 0; mi < 8; ++mi)
#pragma unroll
    for (int ni = 0; ni < 4; ++ni) {
      f32x4 v = acc[mi][ni];
      const int row0 = (wm << 7) + mi * 16 + orow;
      const int col = bn + (wn << 6) + ni * 16 + ocol;
      if (MODE == 2) {
        u16* C = (u16*)Cout;
        size_t base = (size_t)(bm >> 11) * ((size_t)T_DIM * C_DIM) +
                      (size_t)col * T_DIM + (size_t)((bm & 2047) + row0);
        u16x4 o;
        o[0] = f2bf(v[0]); o[1] = f2bf(v[1]); o[2] = f2bf(v[2]); o[3] = f2bf(v[3]);
        *(u16x4*)&C[base] = o;
      } else {
        size_t base = (size_t)(bm + row0) * C_DIM + col;
        if (MODE == 1) {
          float* C = (float*)Cout;
#pragma unroll
          for (int r = 0; r < 4; ++r) C[base + (size_t)r * C_DIM] = v[r];
        } else {
          u16* C = (u16*)Cout;
          const float sc = (MODE == 3) ? QSCALE : 1.0f;
#pragma unroll
          for (int r = 0; r < 4; ++r) C[base + (size_t)r * C_DIM] = f2bf(v[r] * sc);
        }
      }
    }
}

// ------ causal flash attention: 4 waves x 32 q-rows, gload_lds staging -----
// r15 structure; softmax reductions tree-balanced (v_max3-fusable triples).
__global__ __launch_bounds__(256, 2)
void attn_kernel(const u16* __restrict__ Qg, const u16* __restrict__ Kg,
                 const u16* __restrict__ VtG, u16* __restrict__ Y) {
  __shared__ __align__(16) u16 Klds[2][64 * 128];
  __shared__ __align__(16) u16 Vlds[2][128 * 64];
  __shared__ __align__(16) u16 Plds[4][16][72];
  const int f = blockIdx.x;
  const int pair = (f >> 3) & 7;
  const int bh = (f & 7) | ((f >> 6) << 3);   // all 8 pairs of a head on 1 XCD
  const int b = bh >> 4, h = bh & 15;
  const size_t qkbase = (size_t)b * T_DIM * C_DIM + (size_t)h * HD;
  const size_t vtbase = (size_t)b * T_DIM * C_DIM + (size_t)h * HD * T_DIM;
  const int tid = threadIdx.x, wid = tid >> 6, lane = tid & 63;
  const int l15 = lane & 15, g = lane >> 4, l7 = lane & 7;

  const int krow = (wid << 4) + (lane >> 4);
  const u16* Kge = Kg + qkbase + (size_t)krow * C_DIM + (((lane & 15) ^ (lane >> 4)) << 3);
  const u16* Kgo = Kg + qkbase + (size_t)krow * C_DIM + (((lane & 15) ^ 4 ^ (lane >> 4)) << 3);
  const int vrow = (wid << 5) + (lane >> 3);
  const u16* Vgp = VtG + vtbase + (size_t)vrow * T_DIM + (((lane & 7) ^ (lane >> 3)) << 3);

  auto stageK = [&](int buf, int kb) {
    u16* L = &Klds[buf][wid << 11];
    const u16* ge = Kge + (size_t)kb * C_DIM;
    const u16* go = Kgo + (size_t)kb * C_DIM;
    gload16(ge, L);
    gload16(go + (size_t)4 * C_DIM, L + 512);
    gload16(ge + (size_t)8 * C_DIM, L + 1024);
    gload16(go + (size_t)12 * C_DIM, L + 1536);
  };
  auto stageV = [&](int buf, int kb) {
    u16* L = &Vlds[buf][wid << 11];
    const u16* gp = Vgp + kb;
    gload16(gp, L);
    gload16(gp + (size_t)8 * T_DIM, L + 512);
    gload16(gp + (size_t)16 * T_DIM, L + 1024);
    gload16(gp + (size_t)24 * T_DIM, L + 1536);
  };

  auto process = [&](int qb) {
    __syncthreads();            // previous-process reads done before restaging
    const int rlo = qb + wid * 32;
    stageK(0, 0); stageV(0, 0);
    short8 qf[2][4];
#pragma unroll
    for (int rg = 0; rg < 2; ++rg) {
      const u16* qp = Qg + qkbase + (size_t)(rlo + rg * 16 + l15) * C_DIM + g * 8;
#pragma unroll
      for (int dc = 0; dc < 4; ++dc) qf[rg][dc] = *(const short8*)(qp + dc * 32);
    }
    f32x4 zero4 = {0.f, 0.f, 0.f, 0.f};
    f32x4 ao[2][8];
#pragma unroll
    for (int rg = 0; rg < 2; ++rg)
#pragma unroll
      for (int i = 0; i < 8; ++i) ao[rg][i] = zero4;
    float m_run[2] = {-1e30f, -1e30f};
    float l_lane[2] = {0.f, 0.f};
    const int nt = (qb >> 6) + 2;

    int cur = 0;
    for (int t = 0; t < nt; ++t) {
      const int kb = t * 64;
      wait_vm0();                     // own buf[cur] stages (and t=0 qf) landed
      __builtin_amdgcn_s_barrier();   // all waves landed; buf[cur^1] reads done
      if (t + 1 < nt) { stageK(cur ^ 1, kb + 64); stageV(cur ^ 1, kb + 64); }

      if (kb <= rlo + 31) {
        const u16* Kb_ = &Klds[cur][0];
        const u16* Vb_ = &Vlds[cur][0];
        f32x4 st[2][4];
        __builtin_amdgcn_s_setprio(1);
#pragma unroll
        for (int jt = 0; jt < 4; ++jt) {
          short8 kf[4];
#pragma unroll
          for (int dc = 0; dc < 4; ++dc)
            kf[dc] = *(const short8*)&Kb_[(jt * 16 + l15) * 128 + ((((dc << 2) | g) ^ l7) << 3)];
          f32x4 a0 = zero4, a1 = zero4;
#pragma unroll
          for (int dc = 0; dc < 4; ++dc) {
            a0 = __builtin_amdgcn_mfma_f32_16x16x32_bf16(kf[dc], qf[0][dc], a0, 0, 0, 0);
            a1 = __builtin_amdgcn_mfma_f32_16x16x32_bf16(kf[dc], qf[1][dc], a1, 0, 0, 0);
          }
          st[0][jt] = a0; st[1][jt] = a1;
        }
        __builtin_amdgcn_s_setprio(0);

        short8 pf[2][2];
#pragma unroll
        for (int rg = 0; rg < 2; ++rg) {
          const int rbase = rlo + rg * 16;
          if (kb + 63 > rbase) {
            const int qa = rbase + l15;
#pragma unroll
            for (int jt = 0; jt < 4; ++jt) {
              const int k0 = kb + jt * 16 + g * 4;
#pragma unroll
              for (int r = 0; r < 4; ++r)
                if (k0 + r > qa) st[rg][jt][r] = -3e38f;   // exp2 -> exactly 0
            }
          }

          // tree max (v_max3-fusable triples; depth ~3 vs serial 15)
          float ma = fmaxf(fmaxf(st[rg][0][0], st[rg][0][1]),
                           fmaxf(st[rg][0][2], st[rg][0][3]));
          float mb = fmaxf(fmaxf(st[rg][1][0], st[rg][1][1]),
                           fmaxf(st[rg][1][2], st[rg][1][3]));
          float mc = fmaxf(fmaxf(st[rg][2][0], st[rg][2][1]),
                           fmaxf(st[rg][2][2], st[rg][2][3]));
          float md = fmaxf(fmaxf(st[rg][3][0], st[rg][3][1]),
                           fmaxf(st[rg][3][2], st[rg][3][3]));
          float mxl = fmaxf(fmaxf(ma, mb), fmaxf(mc, md));
          if (__any(mxl > m_run[rg] + 8.0f)) {
            float mx = fmaxf(mxl, __shfl_xor(mxl, 16, 64));
            mx = fmaxf(mx, __shfl_xor(mx, 32, 64));
            float mn = fmaxf(m_run[rg], mx);
            float corr = __builtin_amdgcn_exp2f(m_run[rg] - mn);
            m_run[rg] = mn;
#pragma unroll
            for (int dc = 0; dc < 8; ++dc)
#pragma unroll
              for (int r = 0; r < 4; ++r) ao[rg][dc][r] *= corr;
            l_lane[rg] *= corr;
          }

          // P = exp2(S - m); balanced partial sums; pack pairs to Plds
          float sjt[4];
#pragma unroll
          for (int jt = 0; jt < 4; ++jt) {
            float p0 = __builtin_amdgcn_exp2f(st[rg][jt][0] - m_run[rg]);
            float p1 = __builtin_amdgcn_exp2f(st[rg][jt][1] - m_run[rg]);
            float p2 = __builtin_amdgcn_exp2f(st[rg][jt][2] - m_run[rg]);
            float p3 = __builtin_amdgcn_exp2f(st[rg][jt][3] - m_run[rg]);
            sjt[jt] = (p0 + p1) + (p2 + p3);
            u32x2 w;
            w[0] = cvtpk(p0, p1);
            w[1] = cvtpk(p2, p3);
            *(u32x2*)&Plds[wid][l15][jt * 16 + g * 4] = w;
          }
          l_lane[rg] += (sjt[0] + sjt[1]) + (sjt[2] + sjt[3]);
#pragma unroll
          for (int k2 = 0; k2 < 2; ++k2)
            pf[rg][k2] = *(const short8*)&Plds[wid][l15][k2 * 32 + g * 8];
        }

        __builtin_amdgcn_s_setprio(1);
#pragma unroll
        for (int dc = 0; dc < 8; ++dc) {
#pragma unroll
          for (int k2 = 0; k2 < 2; ++k2) {
            short8 vf = *(const short8*)&Vb_[(dc * 16 + l15) * 64 + ((((k2 << 2) | g) ^ l7) << 3)];
            ao[0][dc] = __builtin_amdgcn_mfma_f32_16x16x32_bf16(vf, pf[0][k2], ao[0][dc], 0, 0, 0);
            ao[1][dc] = __builtin_amdgcn_mfma_f32_16x16x32_bf16(vf, pf[1][k2], ao[1][dc], 0, 0, 0);
          }
        }
        __builtin_amdgcn_s_setprio(0);
      }
      cur ^= 1;
    }

#pragma unroll
    for (int rg = 0; rg < 2; ++rg) {
      float l = l_lane[rg];
      l += __shfl_xor(l, 16, 64);
      l += __shfl_xor(l, 32, 64);
      const float rcp = 1.0f / l;
      u16* yp = Y + qkbase + (size_t)(rlo + rg * 16 + l15) * C_DIM + g * 4;
#pragma unroll
      for (int dc = 0; dc < 8; ++dc) {
        u32x2 w;
        w[0] = cvtpk(ao[rg][dc][0] * rcp, ao[rg][dc][1] * rcp);
        w[1] = cvtpk(ao[rg][dc][2] * rcp, ao[rg][dc][3] * rcp);
        *(u32x2*)&yp[dc * 16] = w;
      }
    }
  };

  process(pair * 128);
  process((15 - pair) * 128);
}

extern "C" void kernel_launch(void* const* d_in, const int* in_sizes, int n_in,
                              void* d_out, int out_size, void* d_ws, size_t ws_size,
                              hipStream_t stream) {
  const float* x  = (const float*)d_in[0];
  const float* Wq = (const float*)d_in[1];
  const float* Wk = (const float*)d_in[2];
  const float* Wv = (const float*)d_in[3];
  const float* Wo = (const float*)d_in[4];
  float* out = (float*)d_out;

  const size_t SZX = (size_t)8192 * 2048;
  const size_t SZW = (size_t)2048 * 2048;
  u16* xb  = (u16*)d_ws;
  u16* Wqb = xb + SZX;
  u16* Wkb = Wqb + SZW;
  u16* Wvb = Wkb + SZW;
  u16* Wob = Wvb + SZW;
  u16* Qb  = Wob + SZW;   // Q (pre-scaled), overwritten in place by attn Y
  u16* Kb  = Qb + SZX;
  u16* Vb  = Kb + SZX;    // V^T in [b][n][t] layout

  cast_all_kernel<<<16384, 256, 0, stream>>>(x, Wq, Wk, Wv, Wo, xb, Wqb, Wkb, Wvb, Wob);

  gemm256<3><<<256, 512, 0, stream>>>(xb, Wqb, Qb);  // Q * scale*log2e
  gemm256<0><<<256, 512, 0, stream>>>(xb, Wkb, Kb);
  gemm256<2><<<256, 512, 0, stream>>>(xb, Wvb, Vb);  // V^T out

  attn_kernel<<<512, 256, 0, stream>>>(Qb, Kb, Vb, Qb);

  gemm256<1><<<256, 512, 0, stream>>>(Qb, Wob, out);
}